// Round 6
// baseline (586.146 us; speedup 1.0000x reference)
//
#include <hip/hip_runtime.h>
#include <stdint.h>

// ---------------------------------------------------------------------------
// Fused attention, fp32 I/O, MI355X (gfx950).
// All GEMMs: C = A * B^T (NT), bf16 MFMA, fp32 accumulate.
// fp32 emulation (q/k/score chain): 3 K-segments  Ah*Bh + Al*Bh + Ah*Bl,
// virtual K=3072 with per-segment base pointers.
// gemm256: 256x256, 8 phases/iter, counted vmcnt ladder, and READ-AHEAD
// fragment pipeline: phase p issues ds_reads for phase p+1, waits counted
// lgkmcnt(N) so p's frags are ready while p+1's drain under the MFMA cluster
// (LDS pipe ∥ MFMA pipe overlap — the serialization was the 37%-util wall).
// ---------------------------------------------------------------------------

typedef __bf16 bf16_t;
typedef __bf16 bf16x8 __attribute__((ext_vector_type(8)));
typedef __bf16 bf16x4 __attribute__((ext_vector_type(4)));
typedef float  f32x4  __attribute__((ext_vector_type(4)));
typedef uint32_t u32;

__device__ __forceinline__ void gld_lds16(const void* g, void* l) {
    __builtin_amdgcn_global_load_lds(
        (const __attribute__((address_space(1))) void*)g,
        (__attribute__((address_space(3))) void*)l, 16, 0, 0);
}

// inline-asm LDS read: ordering owned by explicit counted lgkmcnt + SB(0).
__device__ __forceinline__ bf16x8 ld128(const void* p) {
    bf16x8 r;
    const u32 a = (u32)(uintptr_t)(__attribute__((address_space(3))) const void*)p;
    asm volatile("ds_read_b128 %0, %1" : "=v"(r) : "v"(a));
    return r;
}

// ======================= 256^2 read-ahead GEMM (3 K-segments) ===============
// EPI 0: fp32 -> C0[bz*sC + row*ldc + col]
// EPI 2: split hi/lo bf16; col<1024 -> C0/C1 + row*1024+col, col>=1024 ->
//        same + 8388608 elems (the adjacent k-buffer).
template<int EPI>
__global__ __launch_bounds__(512, 2)
void gemm256(const bf16_t* __restrict__ A0, const bf16_t* __restrict__ A1,
             const bf16_t* __restrict__ A2,
             const bf16_t* __restrict__ B0, const bf16_t* __restrict__ B1,
             const bf16_t* __restrict__ B2,
             int NK, int lda, int ldb, long sA, long sB, long sC,
             void* __restrict__ C0v, void* __restrict__ C1v, int ldc,
             int nbx, int plane)
{
    // LDS: 2 buffers x [A0|A1|B0|B1] x 16KB = 128 KiB
    __shared__ __align__(1024) char smem[131072];

    const int nwg = (int)gridDim.x;
    int id = (int)blockIdx.x;
    id = (id & 7) * (nwg >> 3) + (id >> 3);      // XCD-contiguous, bijective
    const int bz  = id / plane;
    const int rem = id - bz * plane;
    const int by  = rem / nbx;
    const int bx  = rem - by * nbx;
    const long bm = (long)by * 256;
    const long bn = (long)bx * 256;
    const long zA = (long)bz * sA, zB = (long)bz * sB;

    const int tid  = threadIdx.x;
    const int lane = tid & 63;
    const int wid  = tid >> 6;        // 8 waves: 2(M) x 4(N)
    const int wr   = wid >> 2;
    const int wc   = wid & 3;
    const int fr   = lane & 15;
    const int kg   = lane >> 4;

    // staging: thread t covers chunk-row t>>3 (+64 via c), 16B chunk t&7, with
    // the 2-bit involution pre-applied to the GLOBAL source.
    const int srow = tid >> 3;
    const int scol = ((tid & 7) ^ ((tid >> 4) & 6)) << 3;   // elems
    const int ldsw = wid << 10;

    // read-side: same involution on the column byte (bits 5 and 6)
    const int swzb    = (fr & 12) << 3;
    const int koff[2] = { (kg * 16) ^ swzb, (64 + kg * 16) ^ swzb };
    const int aBase   = wr * 16384 + fr * 128;
    const int bBase   = 32768 + (wc >> 1) * 16384 + (wc & 1) * 8192 + fr * 128;

    f32x4  acc[8][4] = {};
    bf16x8 bfr[2][4][2];   // [tile parity][fn][kh]
    bf16x8 afr[2][2][2];   // [phase parity][m2][kh]

    auto stage = [&](int kt, int part, int buf) {
        // part: 0=B-half0, 1=B-half1, 2=A-half0, 3=A-half1 (B-first order)
        const int seg    = kt >> 4;              // segLen = 1024 = 16 K-tiles
        const int klocal = (kt & 15) << 6;
        const bool isB = part < 2;
        const bf16_t* base;
        if (isB) base = (seg == 0) ? B0 : (seg == 1 ? B1 : B2);
        else     base = (seg == 0) ? A0 : (seg == 1 ? A1 : A2);
        const long rowb = (isB ? (bn + part * 128) : (bm + (part - 2) * 128)) + srow;
        const long zoff = isB ? zB : zA;
        const int  ld   = isB ? ldb : lda;
        const int  poff = isB ? (32768 + part * 16384) : ((part - 2) * 16384);
        #pragma unroll
        for (int c = 0; c < 2; ++c) {
            const bf16_t* g = base + zoff + (rowb + c * 64) * (long)ld + klocal + scol;
            gld_lds16(g, smem + buf * 65536 + poff + c * 8192 + ldsw);
        }
    };

    // prologue: tile0 {B0,B1,A0,A1} + tile1 {B0,B1,A0} = 7 half-tiles
    #pragma unroll
    for (int ht = 0; ht < 7; ++ht) stage(ht >> 2, ht & 3, (ht >> 2) & 1);
    asm volatile("s_waitcnt vmcnt(6)" ::: "memory");   // tile0 fully in LDS
    __builtin_amdgcn_s_barrier();
    // tile0 B-frags + A-quadrant0 (into bfr[0], afr[0])
    #pragma unroll
    for (int fn = 0; fn < 4; ++fn)
        #pragma unroll
        for (int kh = 0; kh < 2; ++kh)
            bfr[0][fn][kh] = ld128(smem + bBase + fn * 2048 + koff[kh]);
    #pragma unroll
    for (int m2 = 0; m2 < 2; ++m2)
        #pragma unroll
        for (int kh = 0; kh < 2; ++kh)
            afr[0][m2][kh] = ld128(smem + aBase + m2 * 2048 + koff[kh]);

    const int NI = NK >> 1;
    #pragma unroll 1
    for (int i = 0; i < NI; ++i) {
        const bool last = (i == NI - 1);
        #pragma unroll
        for (int p = 0; p < 8; ++p) {
            const int q  = p & 3;
            // ---- stage half-tile H_{8i+7+p} (skip beyond range on last iter)
            if (p == 0 || !last)
                stage(2 * i + ((7 + p) >> 2), (7 + p) & 3, ((7 + p) >> 2) & 1);
            // ---- vmcnt BEFORE the barrier at tile boundaries, so after the
            // barrier every wave's staging of the next tile has landed.
            if (q == 3) {
                if (last) asm volatile("s_waitcnt vmcnt(0)" ::: "memory");
                else      asm volatile("s_waitcnt vmcnt(6)" ::: "memory");
            }
            __builtin_amdgcn_s_barrier();
            // ---- read-ahead: issue phase p+1's fragments
            if (q != 3) {
                const int cb = (p >> 2) * 65536;           // current tile's buf
                #pragma unroll
                for (int m2 = 0; m2 < 2; ++m2)
                    #pragma unroll
                    for (int kh = 0; kh < 2; ++kh)
                        afr[(p + 1) & 1][m2][kh] =
                            ld128(smem + cb + aBase + ((q + 1) * 2 + m2) * 2048 + koff[kh]);
            } else if (!(p == 7 && last)) {
                const int nb = (p == 3) ? 65536 : 0;       // next tile's buf
                #pragma unroll
                for (int fn = 0; fn < 4; ++fn)
                    #pragma unroll
                    for (int kh = 0; kh < 2; ++kh)
                        bfr[(p >> 2) ^ 1][fn][kh] =
                            ld128(smem + nb + bBase + fn * 2048 + koff[kh]);
                #pragma unroll
                for (int m2 = 0; m2 < 2; ++m2)
                    #pragma unroll
                    for (int kh = 0; kh < 2; ++kh)
                        afr[0][m2][kh] =
                            ld128(smem + nb + aBase + m2 * 2048 + koff[kh]);
            }
            __builtin_amdgcn_sched_barrier(0);
            // ---- counted wait: p's frags done; p+1's keep draining under MFMA
            if (q != 3)              asm volatile("s_waitcnt lgkmcnt(4)"  ::: "memory");
            else if (p == 7 && last) asm volatile("s_waitcnt lgkmcnt(0)"  ::: "memory");
            else                     asm volatile("s_waitcnt lgkmcnt(12)" ::: "memory");
            __builtin_amdgcn_sched_barrier(0);
            __builtin_amdgcn_s_setprio(1);
            #pragma unroll
            for (int kh = 0; kh < 2; ++kh)          // kh outer: no same-acc b2b
                #pragma unroll
                for (int m2 = 0; m2 < 2; ++m2)
                    #pragma unroll
                    for (int fn = 0; fn < 4; ++fn)
                        acc[q * 2 + m2][fn] = __builtin_amdgcn_mfma_f32_16x16x32_bf16(
                            afr[p & 1][m2][kh], bfr[p >> 2][fn][kh],
                            acc[q * 2 + m2][fn], 0, 0, 0);
            __builtin_amdgcn_s_setprio(0);
            __builtin_amdgcn_sched_barrier(0);
            __builtin_amdgcn_s_barrier();
        }
    }

    // C/D: col = lane&15, row = (lane>>4)*4 + reg
    const int rq = kg * 4;
    #pragma unroll
    for (int m = 0; m < 8; ++m) {
        #pragma unroll
        for (int fn = 0; fn < 4; ++fn) {
            const long col = bn + wc * 64 + fn * 16 + fr;
            #pragma unroll
            for (int r = 0; r < 4; ++r) {
                const long row = bm + wr * 128 + m * 16 + rq + r;
                const float v = acc[m][fn][r];
                if constexpr (EPI == 0) {
                    ((float*)C0v)[(long)bz * sC + row * ldc + col] = v;
                } else {
                    const bf16_t h  = (bf16_t)v;
                    const float  lo = v - (float)h;
                    const long off = (col >= 1024)
                        ? 8388608L + row * 1024 + (col - 1024)
                        : row * 1024 + col;
                    ((bf16_t*)C0v)[off] = h;
                    ((bf16_t*)C1v)[off] = (bf16_t)lo;
                }
            }
        }
    }
}

// ======================= 128^2 plain GEMM (proven, round 2) =================
#define BM 128
#define BN 128
#define BK 32

template<int EPI>   // 0 = fp32 C ; 1 = bf16 C
__global__ __launch_bounds__(256, 2)
void gemm_nt(const bf16_t* __restrict__ A, const bf16_t* __restrict__ B,
             int K, int lda, int ldb, long sA, long sB, long sC,
             void* __restrict__ C0v, int ldc, int nbx, int nby)
{
    __shared__ bf16_t As[BM * BK];
    __shared__ bf16_t Bs[BN * BK];

    const int nwg = (int)gridDim.x;
    int id = (int)blockIdx.x;
    id = (id & 7) * (nwg >> 3) + (id >> 3);
    const int plane = nbx * nby;
    const int bz  = id / plane;
    const int rem = id - bz * plane;
    const int by  = rem / nbx;
    const int bx  = rem - by * nbx;

    const long bm = (long)by * BM;
    const long bn = (long)bx * BN;

    const bf16_t* A0 = A + (long)bz * sA;
    const bf16_t* B0 = B + (long)bz * sB;

    const int tid  = threadIdx.x;
    const int lane = tid & 63;
    const int wid  = tid >> 6;
    const int wr   = wid >> 1;
    const int wc   = wid & 1;

    const int srow = tid >> 2;
    const int sgc  = (((tid & 3) ^ (srow & 3)) << 3);
    const int ldsb = wid * 512;

    const int fr  = lane & 15;
    const int kgs = (((lane >> 4) ^ (lane & 3)) << 3);

    f32x4 acc[4][4] = {};

    const long arow = (bm + srow) * (long)lda;
    const long brow = (bn + srow) * (long)ldb;

    for (int k0 = 0; k0 < K; k0 += BK) {
        const bf16_t* a = A0 + arow + k0 + sgc;
        const bf16_t* b = B0 + brow + k0 + sgc;
        gld_lds16(a,             &As[ldsb]);
        gld_lds16(a + 64L * lda, &As[2048 + ldsb]);
        gld_lds16(b,             &Bs[ldsb]);
        gld_lds16(b + 64L * ldb, &Bs[2048 + ldsb]);
        __syncthreads();

        bf16x8 af[4], bg[4];
        #pragma unroll
        for (int m = 0; m < 4; ++m)
            af[m] = *(const bf16x8*)&As[(wr * 64 + m * 16 + fr) * BK + kgs];
        #pragma unroll
        for (int n = 0; n < 4; ++n)
            bg[n] = *(const bf16x8*)&Bs[(wc * 64 + n * 16 + fr) * BK + kgs];
        #pragma unroll
        for (int m = 0; m < 4; ++m)
            #pragma unroll
            for (int n = 0; n < 4; ++n)
                acc[m][n] = __builtin_amdgcn_mfma_f32_16x16x32_bf16(
                    af[m], bg[n], acc[m][n], 0, 0, 0);
        __syncthreads();
    }

    const int rq = (lane >> 4) * 4;
    #pragma unroll
    for (int m = 0; m < 4; ++m) {
        #pragma unroll
        for (int n = 0; n < 4; ++n) {
            const long col = bn + wc * 64 + n * 16 + fr;
            #pragma unroll
            for (int r = 0; r < 4; ++r) {
                const long row = bm + wr * 64 + m * 16 + rq + r;
                const long idx = (long)bz * sC + row * ldc + col;
                const float v = acc[m][n][r];
                if constexpr (EPI == 0) ((float*)C0v)[idx]  = v;
                else                    ((bf16_t*)C0v)[idx] = (bf16_t)v;
            }
        }
    }
}

// =========================== helpers ========================================
template<bool SPLIT>
__global__ __launch_bounds__(256)
void cvt_f32_bf16(const float* __restrict__ X, bf16_t* __restrict__ Hh,
                  bf16_t* __restrict__ Ll, int n)
{
    const int i = (blockIdx.x * 256 + threadIdx.x) * 4;
    if (i >= n) return;
    const f32x4 v = *(const f32x4*)&X[i];
    bf16x4 h, l;
    #pragma unroll
    for (int j = 0; j < 4; ++j) {
        h[j] = (bf16_t)v[j];
        if constexpr (SPLIT) l[j] = (bf16_t)(v[j] - (float)h[j]);
    }
    *(bf16x4*)&Hh[i] = h;
    if constexpr (SPLIT) *(bf16x4*)&Ll[i] = l;
}

__global__ __launch_bounds__(256)
void softmax_rows(const float* __restrict__ Sc, bf16_t* __restrict__ P)
{
    constexpr int NC = 2048;
    const int row = blockIdx.x;
    const int tid = threadIdx.x;
    const float* s = Sc + (size_t)row * NC;

    float v[8];
    *(f32x4*)&v[0] = *(const f32x4*)&s[tid * 8];
    *(f32x4*)&v[4] = *(const f32x4*)&s[tid * 8 + 4];

    float m = v[0];
    #pragma unroll
    for (int j = 1; j < 8; ++j) m = fmaxf(m, v[j]);
    #pragma unroll
    for (int off = 1; off < 64; off <<= 1) m = fmaxf(m, __shfl_xor(m, off));

    __shared__ float redm[4], reds[4];
    if ((tid & 63) == 0) redm[tid >> 6] = m;
    __syncthreads();
    m = fmaxf(fmaxf(redm[0], redm[1]), fmaxf(redm[2], redm[3]));

    float sum = 0.f;
    #pragma unroll
    for (int j = 0; j < 8; ++j) { v[j] = __expf(v[j] - m); sum += v[j]; }
    #pragma unroll
    for (int off = 1; off < 64; off <<= 1) sum += __shfl_xor(sum, off);
    if ((tid & 63) == 0) reds[tid >> 6] = sum;
    __syncthreads();
    sum = reds[0] + reds[1] + reds[2] + reds[3];

    const float inv = 1.0f / sum;
    bf16x8 o;
    #pragma unroll
    for (int j = 0; j < 8; ++j) o[j] = (bf16_t)(v[j] * inv);
    *(bf16x8*)(P + (size_t)row * NC + tid * 8) = o;
}

// =========================== driver =========================================
extern "C" void kernel_launch(void* const* d_in, const int* in_sizes, int n_in,
                              void* d_out, int out_size, void* d_ws, size_t ws_size,
                              hipStream_t stream)
{
    const float* x  = (const float*)d_in[0];
    const float* Wq = (const float*)d_in[1];
    const float* Wk = (const float*)d_in[2];
    const float* Wv = (const float*)d_in[3];
    const float* Wo = (const float*)d_in[4];
    float* out = (float*)d_out;

    constexpr long H = 1024, S = 2048, B = 4, NT = B * S;   // 8192 tokens
    constexpr long HH = H * H;

    // Workspace (peak footprint 146 MB, stream-ordered aliasing):
    //  [0,16)   xh        -> later score [0,64) fp32
    //  [16,32)  xl
    //  [32,36)  whi [2048][1024] (Wq rows 0-1023, Wk rows 1024-2047)
    //  [36,40)  wlo
    //  [40,42)  wv
    //  [64,80)  qh   -> later P [64,96) bf16
    //  [80,96)  kh
    //  [96,112) ql   -> later attn [96,112)
    //  [112,128) kl
    //  [128,144) vT [1024][8192]
    //  [144,146) wo
    char* ws = (char*)d_ws;
    const size_t MB = 1u << 20;
    bf16_t* xh    = (bf16_t*)(ws + 0);
    bf16_t* xl    = (bf16_t*)(ws + 16 * MB);
    bf16_t* whi   = (bf16_t*)(ws + 32 * MB);
    bf16_t* wlo   = (bf16_t*)(ws + 36 * MB);
    bf16_t* wv    = (bf16_t*)(ws + 40 * MB);
    float*  score = (float*) (ws + 0);
    bf16_t* qh    = (bf16_t*)(ws + 64 * MB);
    bf16_t* kh    = (bf16_t*)(ws + 80 * MB);   // = qh + 8388608 elems
    bf16_t* ql    = (bf16_t*)(ws + 96 * MB);
    bf16_t* kl    = (bf16_t*)(ws + 112 * MB);  // = ql + 8388608 elems
    bf16_t* P     = (bf16_t*)(ws + 64 * MB);
    bf16_t* attn  = (bf16_t*)(ws + 96 * MB);
    bf16_t* vT    = (bf16_t*)(ws + 128 * MB);
    bf16_t* wo    = (bf16_t*)(ws + 144 * MB);

    const dim3 blk(256);

    // conversions / splits
    cvt_f32_bf16<true ><<<NT * H / 1024, blk, 0, stream>>>(x,  xh, xl, NT * H);
    cvt_f32_bf16<true ><<<HH / 1024, blk, 0, stream>>>(Wq, whi,      wlo,      HH);
    cvt_f32_bf16<true ><<<HH / 1024, blk, 0, stream>>>(Wk, whi + HH, wlo + HH, HH);
    cvt_f32_bf16<false><<<HH / 1024, blk, 0, stream>>>(Wv, wv, nullptr, HH);
    cvt_f32_bf16<false><<<HH / 1024, blk, 0, stream>>>(Wo, wo, nullptr, HH);

    // q,k projection: [8192][3072] x [2048][3072]^T, split epilogue
    gemm256<2><<<dim3(256), dim3(512), 0, stream>>>(
        xh, xl, xh, whi, whi, wlo, 48, (int)H, (int)H, 0L, 0L, 0L,
        qh, ql, (int)H, 8, 256);

    // vT[e,t] = sum_d Wv[e,d] x[t,d]
    gemm_nt<1><<<dim3(512), blk, 0, stream>>>(
        wv, xh, (int)H, (int)H, (int)H, 0L, 0L, 0L, vT, (int)NT, 64, 8);

    // score = q k^T (4 batches, virtual K=3072, fp32 out, unscaled)
    gemm256<0><<<dim3(256), dim3(512), 0, stream>>>(
        qh, ql, qh, kh, kh, kl, 48, (int)H, (int)H,
        S * H, S * H, S * S, score, nullptr, (int)S, 8, 64);

    // softmax rows (all batches)
    softmax_rows<<<dim3(B * S), blk, 0, stream>>>(score, P);

    // attn = P v  ==  P * (vT batch-slice)^T
    gemm_nt<1><<<dim3(512), blk, 0, stream>>>(
        P, vT, (int)S, (int)S, (int)NT, S * S, S, S * H, attn, (int)H, 8, 16);

    // out = attn Wo^T
    gemm_nt<0><<<dim3(512), blk, 0, stream>>>(
        attn, wo, (int)H, (int)H, (int)H, 0L, 0L, 0L, out, (int)H, 8, 64);
}

// Round 7
// 251.792 us; speedup vs baseline: 2.3279x; 2.3279x over previous
//
#include <hip/hip_runtime.h>
#include <stdint.h>

// ---------------------------------------------------------------------------
// Fused attention, fp32 I/O, MI355X (gfx950).
// All GEMMs: C = A * B^T (NT), fp16 MFMA (11 mantissa bits), fp32 accumulate.
// Precision plan (re-derived for fp16):
//   qkproj: 2 segments (xh*W + xl*W), virtual K=2048 -> q,k at ~fp32 grade
//   score : 1 segment  (qh*kh), K=1024 -> logit err ~9e-3 std (<< softmax scale)
//   v/P/attn/out path: plain fp16 (4x tighter than bf16)
// gemm256 = round-5 structure verbatim (8-phase, counted vmcnt ladder, asm
// ds_read, 2-bit XOR swizzle) -- only dtype + epilogue changed.
// ---------------------------------------------------------------------------

typedef _Float16 f16_t;
typedef _Float16 f16x8 __attribute__((ext_vector_type(8)));
typedef _Float16 f16x4 __attribute__((ext_vector_type(4)));
typedef float    f32x4 __attribute__((ext_vector_type(4)));
typedef uint32_t u32;

__device__ __forceinline__ void gld_lds16(const void* g, void* l) {
    __builtin_amdgcn_global_load_lds(
        (const __attribute__((address_space(1))) void*)g,
        (__attribute__((address_space(3))) void*)l, 16, 0, 0);
}

// inline-asm LDS read (ordering owned by explicit waits/barriers as in r5)
__device__ __forceinline__ f16x8 ld128(const void* p) {
    f16x8 r;
    const u32 a = (u32)(uintptr_t)(__attribute__((address_space(3))) const void*)p;
    asm volatile("ds_read_b128 %0, %1" : "=v"(r) : "v"(a));
    return r;
}

// ======================= 256^2 8-phase GEMM (K-segments) ====================
// EPI 0: fp32 -> C0[bz*sC + row*ldc + col]
// EPI 3: fp16 col-split: col<1024 -> C0[row*1024+col], col>=1024 ->
//        C0[8388608 + row*1024 + (col-1024)]  (adjacent 16MB buffer).
template<int EPI>
__global__ __launch_bounds__(512, 2)
void gemm256(const f16_t* __restrict__ A0, const f16_t* __restrict__ A1,
             const f16_t* __restrict__ A2,
             const f16_t* __restrict__ B0, const f16_t* __restrict__ B1,
             const f16_t* __restrict__ B2,
             int NK, int lda, int ldb, long sA, long sB, long sC,
             void* __restrict__ C0v, int ldc,
             int nbx, int plane)
{
    // LDS: 2 buffers x [A0|A1|B0|B1] x 16KB = 128 KiB
    __shared__ __align__(1024) char smem[131072];

    const int nwg = (int)gridDim.x;
    int id = (int)blockIdx.x;
    id = (id & 7) * (nwg >> 3) + (id >> 3);      // XCD-contiguous, bijective
    const int bz  = id / plane;
    const int rem = id - bz * plane;
    const int by  = rem / nbx;
    const int bx  = rem - by * nbx;
    const long bm = (long)by * 256;
    const long bn = (long)bx * 256;
    const long zA = (long)bz * sA, zB = (long)bz * sB;

    const int tid  = threadIdx.x;
    const int lane = tid & 63;
    const int wid  = tid >> 6;        // 8 waves: 2(M) x 4(N)
    const int wr   = wid >> 2;
    const int wc   = wid & 3;
    const int fr   = lane & 15;
    const int kg   = lane >> 4;

    // staging: thread t covers chunk-row t>>3 (+64 via c), 16B chunk t&7, with
    // the 2-bit involution pre-applied to the GLOBAL source.
    const int srow = tid >> 3;
    const int scol = ((tid & 7) ^ ((tid >> 4) & 6)) << 3;   // elems
    const int ldsw = wid << 10;

    // read-side: same involution on the column byte (bits 5 and 6)
    const int swzb    = (fr & 12) << 3;
    const int koff[2] = { (kg * 16) ^ swzb, (64 + kg * 16) ^ swzb };
    const int aBase   = wr * 16384 + fr * 128;
    const int bBase   = 32768 + (wc >> 1) * 16384 + (wc & 1) * 8192 + fr * 128;

    f32x4 acc[8][4] = {};
    f16x8 bfr[4][2];

    auto stage = [&](int kt, int part, int buf) {
        // part: 0=B-half0, 1=B-half1, 2=A-half0, 3=A-half1 (B-first order)
        const int seg    = kt >> 4;              // segLen = 1024 = 16 K-tiles
        const int klocal = (kt & 15) << 6;
        const bool isB = part < 2;
        const f16_t* base;
        if (isB) base = (seg == 0) ? B0 : (seg == 1 ? B1 : B2);
        else     base = (seg == 0) ? A0 : (seg == 1 ? A1 : A2);
        const long rowb = (isB ? (bn + part * 128) : (bm + (part - 2) * 128)) + srow;
        const long zoff = isB ? zB : zA;
        const int  ld   = isB ? ldb : lda;
        const int  poff = isB ? (32768 + part * 16384) : ((part - 2) * 16384);
        #pragma unroll
        for (int c = 0; c < 2; ++c) {
            const f16_t* g = base + zoff + (rowb + c * 64) * (long)ld + klocal + scol;
            gld_lds16(g, smem + buf * 65536 + poff + c * 8192 + ldsw);
        }
    };

    // prologue: tile0 {B0,B1,A0,A1} + tile1 {B0,B1,A0} = 7 half-tiles
    #pragma unroll
    for (int ht = 0; ht < 7; ++ht) stage(ht >> 2, ht & 3, (ht >> 2) & 1);
    asm volatile("s_waitcnt vmcnt(6)" ::: "memory");
    __builtin_amdgcn_s_barrier();

    const int NI = NK >> 1;
    #pragma unroll 1
    for (int i = 0; i < NI; ++i) {
        const bool last = (i == NI - 1);
        #pragma unroll
        for (int p = 0; p < 8; ++p) {
            const int q  = p & 3;
            const int cb = (p >> 2) * 65536;     // 0: tile 2i (buf0), 1: 2i+1
            if (q == 0) {                        // B-frags for this K-tile
                #pragma unroll
                for (int fn = 0; fn < 4; ++fn)
                    #pragma unroll
                    for (int kh = 0; kh < 2; ++kh)
                        bfr[fn][kh] = ld128(smem + cb + bBase
                                            + fn * 2048 + koff[kh]);
            }
            f16x8 afr[2][2];                     // A-frags, quadrant q
            #pragma unroll
            for (int m2 = 0; m2 < 2; ++m2)
                #pragma unroll
                for (int kh = 0; kh < 2; ++kh)
                    afr[m2][kh] = ld128(smem + cb + aBase
                                        + (q * 2 + m2) * 2048 + koff[kh]);
            // stage half-tile H_{8i+7+p}
            const int sc = (7 + p) >> 2;         // 1..3
            if (p == 0 || !last) stage(2 * i + sc, (7 + p) & 3, sc & 1);
            __builtin_amdgcn_sched_barrier(0);
            __builtin_amdgcn_s_barrier();
            asm volatile("s_waitcnt lgkmcnt(0)" ::: "memory");
            __builtin_amdgcn_sched_barrier(0);   // rule #18: pin MFMA below wait
            __builtin_amdgcn_s_setprio(1);
            #pragma unroll
            for (int m2 = 0; m2 < 2; ++m2)
                #pragma unroll
                for (int fn = 0; fn < 4; ++fn)
                    #pragma unroll
                    for (int kh = 0; kh < 2; ++kh)
                        acc[q * 2 + m2][fn] = __builtin_amdgcn_mfma_f32_16x16x32_f16(
                            afr[m2][kh], bfr[fn][kh], acc[q * 2 + m2][fn], 0, 0, 0);
            __builtin_amdgcn_s_setprio(0);
            __builtin_amdgcn_sched_barrier(0);   // keep MFMA inside the phase
            if (q == 3) {                        // counted vmcnt, never 0 mid-loop
                if (last) asm volatile("s_waitcnt vmcnt(0)" ::: "memory");
                else      asm volatile("s_waitcnt vmcnt(6)" ::: "memory");
            }
            __builtin_amdgcn_s_barrier();
        }
    }

    // C/D: col = lane&15, row = (lane>>4)*4 + reg
    const int rq = kg * 4;
    #pragma unroll
    for (int m = 0; m < 8; ++m) {
        #pragma unroll
        for (int fn = 0; fn < 4; ++fn) {
            const long col = bn + wc * 64 + fn * 16 + fr;
            #pragma unroll
            for (int r = 0; r < 4; ++r) {
                const long row = bm + wr * 128 + m * 16 + rq + r;
                const float v = acc[m][fn][r];
                if constexpr (EPI == 0) {
                    ((float*)C0v)[(long)bz * sC + row * ldc + col] = v;
                } else {
                    const long off = (col >= 1024)
                        ? 8388608L + row * 1024 + (col - 1024)
                        : row * 1024 + col;
                    ((f16_t*)C0v)[off] = (f16_t)v;
                }
            }
        }
    }
}

// ======================= 128^2 plain GEMM (proven, round 2) =================
#define BM 128
#define BN 128
#define BK 32

template<int EPI>   // 0 = fp32 C ; 1 = fp16 C
__global__ __launch_bounds__(256, 2)
void gemm_nt(const f16_t* __restrict__ A, const f16_t* __restrict__ B,
             int K, int lda, int ldb, long sA, long sB, long sC,
             void* __restrict__ C0v, int ldc, int nbx, int nby)
{
    __shared__ f16_t As[BM * BK];
    __shared__ f16_t Bs[BN * BK];

    const int nwg = (int)gridDim.x;
    int id = (int)blockIdx.x;
    id = (id & 7) * (nwg >> 3) + (id >> 3);
    const int plane = nbx * nby;
    const int bz  = id / plane;
    const int rem = id - bz * plane;
    const int by  = rem / nbx;
    const int bx  = rem - by * nbx;

    const long bm = (long)by * BM;
    const long bn = (long)bx * BN;

    const f16_t* A0 = A + (long)bz * sA;
    const f16_t* B0 = B + (long)bz * sB;

    const int tid  = threadIdx.x;
    const int lane = tid & 63;
    const int wid  = tid >> 6;
    const int wr   = wid >> 1;
    const int wc   = wid & 1;

    const int srow = tid >> 2;
    const int sgc  = (((tid & 3) ^ (srow & 3)) << 3);
    const int ldsb = wid * 512;

    const int fr  = lane & 15;
    const int kgs = (((lane >> 4) ^ (lane & 3)) << 3);

    f32x4 acc[4][4] = {};

    const long arow = (bm + srow) * (long)lda;
    const long brow = (bn + srow) * (long)ldb;

    for (int k0 = 0; k0 < K; k0 += BK) {
        const f16_t* a = A0 + arow + k0 + sgc;
        const f16_t* b = B0 + brow + k0 + sgc;
        gld_lds16(a,             &As[ldsb]);
        gld_lds16(a + 64L * lda, &As[2048 + ldsb]);
        gld_lds16(b,             &Bs[ldsb]);
        gld_lds16(b + 64L * ldb, &Bs[2048 + ldsb]);
        __syncthreads();

        f16x8 af[4], bg[4];
        #pragma unroll
        for (int m = 0; m < 4; ++m)
            af[m] = *(const f16x8*)&As[(wr * 64 + m * 16 + fr) * BK + kgs];
        #pragma unroll
        for (int n = 0; n < 4; ++n)
            bg[n] = *(const f16x8*)&Bs[(wc * 64 + n * 16 + fr) * BK + kgs];
        #pragma unroll
        for (int m = 0; m < 4; ++m)
            #pragma unroll
            for (int n = 0; n < 4; ++n)
                acc[m][n] = __builtin_amdgcn_mfma_f32_16x16x32_f16(
                    af[m], bg[n], acc[m][n], 0, 0, 0);
        __syncthreads();
    }

    const int rq = (lane >> 4) * 4;
    #pragma unroll
    for (int m = 0; m < 4; ++m) {
        #pragma unroll
        for (int n = 0; n < 4; ++n) {
            const long col = bn + wc * 64 + n * 16 + fr;
            #pragma unroll
            for (int r = 0; r < 4; ++r) {
                const long row = bm + wr * 64 + m * 16 + rq + r;
                const long idx = (long)bz * sC + row * ldc + col;
                const float v = acc[m][n][r];
                if constexpr (EPI == 0) ((float*)C0v)[idx] = v;
                else                    ((f16_t*)C0v)[idx] = (f16_t)v;
            }
        }
    }
}

// =========================== helpers ========================================
template<bool SPLIT>
__global__ __launch_bounds__(256)
void cvt_f32_f16(const float* __restrict__ X, f16_t* __restrict__ Hh,
                 f16_t* __restrict__ Ll, int n)
{
    const int i = (blockIdx.x * 256 + threadIdx.x) * 4;
    if (i >= n) return;
    const f32x4 v = *(const f32x4*)&X[i];
    f16x4 h, l;
    #pragma unroll
    for (int j = 0; j < 4; ++j) {
        h[j] = (f16_t)v[j];
        if constexpr (SPLIT) l[j] = (f16_t)(v[j] - (float)h[j]);
    }
    *(f16x4*)&Hh[i] = h;
    if constexpr (SPLIT) *(f16x4*)&Ll[i] = l;
}

// row softmax over 2048 cols; one 256-thread block per row; fp32 in, fp16 out
__global__ __launch_bounds__(256)
void softmax_rows(const float* __restrict__ Sc, f16_t* __restrict__ P)
{
    constexpr int NC = 2048;
    const int row = blockIdx.x;
    const int tid = threadIdx.x;
    const float* s = Sc + (size_t)row * NC;

    float v[8];
    *(f32x4*)&v[0] = *(const f32x4*)&s[tid * 8];
    *(f32x4*)&v[4] = *(const f32x4*)&s[tid * 8 + 4];

    float m = v[0];
    #pragma unroll
    for (int j = 1; j < 8; ++j) m = fmaxf(m, v[j]);
    #pragma unroll
    for (int off = 1; off < 64; off <<= 1) m = fmaxf(m, __shfl_xor(m, off));

    __shared__ float redm[4], reds[4];
    if ((tid & 63) == 0) redm[tid >> 6] = m;
    __syncthreads();
    m = fmaxf(fmaxf(redm[0], redm[1]), fmaxf(redm[2], redm[3]));

    float sum = 0.f;
    #pragma unroll
    for (int j = 0; j < 8; ++j) { v[j] = __expf(v[j] - m); sum += v[j]; }
    #pragma unroll
    for (int off = 1; off < 64; off <<= 1) sum += __shfl_xor(sum, off);
    if ((tid & 63) == 0) reds[tid >> 6] = sum;
    __syncthreads();
    sum = reds[0] + reds[1] + reds[2] + reds[3];

    const float inv = 1.0f / sum;
    f16x8 o;
    #pragma unroll
    for (int j = 0; j < 8; ++j) o[j] = (f16_t)(v[j] * inv);
    *(f16x8*)(P + (size_t)row * NC + tid * 8) = o;
}

// =========================== driver =========================================
extern "C" void kernel_launch(void* const* d_in, const int* in_sizes, int n_in,
                              void* d_out, int out_size, void* d_ws, size_t ws_size,
                              hipStream_t stream)
{
    const float* x  = (const float*)d_in[0];
    const float* Wq = (const float*)d_in[1];
    const float* Wk = (const float*)d_in[2];
    const float* Wv = (const float*)d_in[3];
    const float* Wo = (const float*)d_in[4];
    float* out = (float*)d_out;

    constexpr long H = 1024, S = 2048, B = 4, NT = B * S;   // 8192 tokens
    constexpr long HH = H * H;

    // Workspace (peak 152 MB, stream-ordered aliasing):
    //  [0,16)    xh fp16          -> later score fp32 [0,64)
    //  [64,68)   wqk fp16 [2048][1024] (Wq rows 0-1023, Wk rows 1024-2047)
    //  [68,70)   wv   [70,72) wo
    //  [72,88)   qh fp16  -> later attn [72,88)
    //  [88,104)  kh fp16  (= qh + 8388608 elems)
    //  [104,120) vT fp16 [1024][8192]
    //  [120,136) xl fp16 -> later P [120,152)
    char* ws = (char*)d_ws;
    const size_t MB = 1u << 20;
    f16_t* xh    = (f16_t*)(ws + 0);
    float* score = (float*)(ws + 0);
    f16_t* wqk   = (f16_t*)(ws + 64 * MB);
    f16_t* wv    = (f16_t*)(ws + 68 * MB);
    f16_t* wo    = (f16_t*)(ws + 70 * MB);
    f16_t* qh    = (f16_t*)(ws + 72 * MB);
    f16_t* kh    = (f16_t*)(ws + 88 * MB);   // = qh + 8388608
    f16_t* attn  = (f16_t*)(ws + 72 * MB);   // after score (qh/kh dead)
    f16_t* vT    = (f16_t*)(ws + 104 * MB);
    f16_t* xl    = (f16_t*)(ws + 120 * MB);
    f16_t* P     = (f16_t*)(ws + 120 * MB);  // after qkproj (xl dead)

    const dim3 blk(256);

    // conversions
    cvt_f32_f16<true ><<<NT * H / 1024, blk, 0, stream>>>(x,  xh, xl, NT * H);
    cvt_f32_f16<false><<<HH / 1024, blk, 0, stream>>>(Wq, wqk,      nullptr, HH);
    cvt_f32_f16<false><<<HH / 1024, blk, 0, stream>>>(Wk, wqk + HH, nullptr, HH);
    cvt_f32_f16<false><<<HH / 1024, blk, 0, stream>>>(Wv, wv, nullptr, HH);
    cvt_f32_f16<false><<<HH / 1024, blk, 0, stream>>>(Wo, wo, nullptr, HH);

    // q,k projection: 2 segments (xh*W + xl*W), virtual K=2048, fp16 col-split
    gemm256<3><<<dim3(256), dim3(512), 0, stream>>>(
        xh, xl, xh, wqk, wqk, wqk, 32, (int)H, (int)H, 0L, 0L, 0L,
        qh, (int)H, 8, 256);

    // vT[e,t] = sum_d Wv[e,d] x[t,d]
    gemm_nt<1><<<dim3(512), blk, 0, stream>>>(
        wv, xh, (int)H, (int)H, (int)H, 0L, 0L, 0L, vT, (int)NT, 64, 8);

    // score = q k^T, 1 segment fp16, all 4 batches (fp32 out, unscaled)
    gemm256<0><<<dim3(256), dim3(512), 0, stream>>>(
        qh, qh, qh, kh, kh, kh, 16, (int)H, (int)H,
        S * H, S * H, S * S, score, (int)S, 8, 64);

    // softmax rows (all batches)
    softmax_rows<<<dim3(B * S), blk, 0, stream>>>(score, P);

    // attn = P v  ==  P * (vT batch-slice)^T
    gemm_nt<1><<<dim3(512), blk, 0, stream>>>(
        P, vT, (int)S, (int)S, (int)NT, S * S, S, S * H, attn, (int)H, 8, 16);

    // out = attn Wo^T
    gemm_nt<0><<<dim3(512), blk, 0, stream>>>(
        attn, wo, (int)H, (int)H, (int)H, 0L, 0L, 0L, out, (int)H, 8, 64);
}

// Round 8
// 242.529 us; speedup vs baseline: 2.4168x; 1.0382x over previous
//
#include <hip/hip_runtime.h>
#include <stdint.h>

// ---------------------------------------------------------------------------
// Fused attention, fp32 I/O, MI355X (gfx950).
// All GEMMs: C = A * B^T (NT), fp16 MFMA, fp32 accumulate.
//   qkproj: 2 segments (xh*W + xl*W), virtual K=2048 -> q,k at ~fp32 grade
//   score : 1 segment  (qh*kh), K=1024
//   output chain folded: out = P*(x*(Wo*Wv)^T)^T  -- Wvo=Wo*Wv precomputed,
//   uT = Wvo*x^T (old vproj shape), PV writes fp32 out directly. Saves the
//   17.2 GF output projection + attn materialization.
// gemm256 = round-5 structure (8-phase, counted vmcnt, asm ds_read, swizzle).
// ---------------------------------------------------------------------------

typedef _Float16 f16_t;
typedef _Float16 f16x8 __attribute__((ext_vector_type(8)));
typedef _Float16 f16x4 __attribute__((ext_vector_type(4)));
typedef float    f32x4 __attribute__((ext_vector_type(4)));
typedef uint32_t u32;

__device__ __forceinline__ void gld_lds16(const void* g, void* l) {
    __builtin_amdgcn_global_load_lds(
        (const __attribute__((address_space(1))) void*)g,
        (__attribute__((address_space(3))) void*)l, 16, 0, 0);
}

__device__ __forceinline__ f16x8 ld128(const void* p) {
    f16x8 r;
    const u32 a = (u32)(uintptr_t)(__attribute__((address_space(3))) const void*)p;
    asm volatile("ds_read_b128 %0, %1" : "=v"(r) : "v"(a));
    return r;
}

// ======================= 256^2 8-phase GEMM (K-segments) ====================
// EPI 0: fp32 -> C0[bz*sC + row*ldc + col]
// EPI 3: fp16 col-split: col<1024 -> C0[row*1024+col], col>=1024 ->
//        C0[8388608 + row*1024 + (col-1024)]  (adjacent 16MB buffer).
template<int EPI>
__global__ __launch_bounds__(512, 2)
void gemm256(const f16_t* __restrict__ A0, const f16_t* __restrict__ A1,
             const f16_t* __restrict__ A2,
             const f16_t* __restrict__ B0, const f16_t* __restrict__ B1,
             const f16_t* __restrict__ B2,
             int NK, int lda, int ldb, long sA, long sB, long sC,
             void* __restrict__ C0v, int ldc,
             int nbx, int plane)
{
    __shared__ __align__(1024) char smem[131072];

    const int nwg = (int)gridDim.x;
    int id = (int)blockIdx.x;
    id = (id & 7) * (nwg >> 3) + (id >> 3);
    const int bz  = id / plane;
    const int rem = id - bz * plane;
    const int by  = rem / nbx;
    const int bx  = rem - by * nbx;
    const long bm = (long)by * 256;
    const long bn = (long)bx * 256;
    const long zA = (long)bz * sA, zB = (long)bz * sB;

    const int tid  = threadIdx.x;
    const int lane = tid & 63;
    const int wid  = tid >> 6;
    const int wr   = wid >> 2;
    const int wc   = wid & 3;
    const int fr   = lane & 15;
    const int kg   = lane >> 4;

    const int srow = tid >> 3;
    const int scol = ((tid & 7) ^ ((tid >> 4) & 6)) << 3;
    const int ldsw = wid << 10;

    const int swzb    = (fr & 12) << 3;
    const int koff[2] = { (kg * 16) ^ swzb, (64 + kg * 16) ^ swzb };
    const int aBase   = wr * 16384 + fr * 128;
    const int bBase   = 32768 + (wc >> 1) * 16384 + (wc & 1) * 8192 + fr * 128;

    f32x4 acc[8][4] = {};
    f16x8 bfr[4][2];

    auto stage = [&](int kt, int part, int buf) {
        const int seg    = kt >> 4;
        const int klocal = (kt & 15) << 6;
        const bool isB = part < 2;
        const f16_t* base;
        if (isB) base = (seg == 0) ? B0 : (seg == 1 ? B1 : B2);
        else     base = (seg == 0) ? A0 : (seg == 1 ? A1 : A2);
        const long rowb = (isB ? (bn + part * 128) : (bm + (part - 2) * 128)) + srow;
        const long zoff = isB ? zB : zA;
        const int  ld   = isB ? ldb : lda;
        const int  poff = isB ? (32768 + part * 16384) : ((part - 2) * 16384);
        #pragma unroll
        for (int c = 0; c < 2; ++c) {
            const f16_t* g = base + zoff + (rowb + c * 64) * (long)ld + klocal + scol;
            gld_lds16(g, smem + buf * 65536 + poff + c * 8192 + ldsw);
        }
    };

    #pragma unroll
    for (int ht = 0; ht < 7; ++ht) stage(ht >> 2, ht & 3, (ht >> 2) & 1);
    asm volatile("s_waitcnt vmcnt(6)" ::: "memory");
    __builtin_amdgcn_s_barrier();

    const int NI = NK >> 1;
    #pragma unroll 1
    for (int i = 0; i < NI; ++i) {
        const bool last = (i == NI - 1);
        #pragma unroll
        for (int p = 0; p < 8; ++p) {
            const int q  = p & 3;
            const int cb = (p >> 2) * 65536;
            if (q == 0) {
                #pragma unroll
                for (int fn = 0; fn < 4; ++fn)
                    #pragma unroll
                    for (int kh = 0; kh < 2; ++kh)
                        bfr[fn][kh] = ld128(smem + cb + bBase
                                            + fn * 2048 + koff[kh]);
            }
            f16x8 afr[2][2];
            #pragma unroll
            for (int m2 = 0; m2 < 2; ++m2)
                #pragma unroll
                for (int kh = 0; kh < 2; ++kh)
                    afr[m2][kh] = ld128(smem + cb + aBase
                                        + (q * 2 + m2) * 2048 + koff[kh]);
            const int sc = (7 + p) >> 2;
            if (p == 0 || !last) stage(2 * i + sc, (7 + p) & 3, sc & 1);
            __builtin_amdgcn_sched_barrier(0);
            __builtin_amdgcn_s_barrier();
            asm volatile("s_waitcnt lgkmcnt(0)" ::: "memory");
            __builtin_amdgcn_sched_barrier(0);
            __builtin_amdgcn_s_setprio(1);
            #pragma unroll
            for (int m2 = 0; m2 < 2; ++m2)
                #pragma unroll
                for (int fn = 0; fn < 4; ++fn)
                    #pragma unroll
                    for (int kh = 0; kh < 2; ++kh)
                        acc[q * 2 + m2][fn] = __builtin_amdgcn_mfma_f32_16x16x32_f16(
                            afr[m2][kh], bfr[fn][kh], acc[q * 2 + m2][fn], 0, 0, 0);
            __builtin_amdgcn_s_setprio(0);
            __builtin_amdgcn_sched_barrier(0);
            if (q == 3) {
                if (last) asm volatile("s_waitcnt vmcnt(0)" ::: "memory");
                else      asm volatile("s_waitcnt vmcnt(6)" ::: "memory");
            }
            __builtin_amdgcn_s_barrier();
        }
    }

    const int rq = kg * 4;
    #pragma unroll
    for (int m = 0; m < 8; ++m) {
        #pragma unroll
        for (int fn = 0; fn < 4; ++fn) {
            const long col = bn + wc * 64 + fn * 16 + fr;
            #pragma unroll
            for (int r = 0; r < 4; ++r) {
                const long row = bm + wr * 128 + m * 16 + rq + r;
                const float v = acc[m][fn][r];
                if constexpr (EPI == 0) {
                    ((float*)C0v)[(long)bz * sC + row * ldc + col] = v;
                } else {
                    const long off = (col >= 1024)
                        ? 8388608L + row * 1024 + (col - 1024)
                        : row * 1024 + col;
                    ((f16_t*)C0v)[off] = (f16_t)v;
                }
            }
        }
    }
}

// ======================= 128^2 plain GEMM (proven) ==========================
#define BM 128
#define BN 128
#define BK 32

template<int EPI>   // 0 = fp32 C ; 1 = fp16 C
__global__ __launch_bounds__(256, 2)
void gemm_nt(const f16_t* __restrict__ A, const f16_t* __restrict__ B,
             int K, int lda, int ldb, long sA, long sB, long sC,
             void* __restrict__ C0v, int ldc, int nbx, int nby)
{
    __shared__ f16_t As[BM * BK];
    __shared__ f16_t Bs[BN * BK];

    const int nwg = (int)gridDim.x;
    int id = (int)blockIdx.x;
    id = (id & 7) * (nwg >> 3) + (id >> 3);
    const int plane = nbx * nby;
    const int bz  = id / plane;
    const int rem = id - bz * plane;
    const int by  = rem / nbx;
    const int bx  = rem - by * nbx;

    const long bm = (long)by * BM;
    const long bn = (long)bx * BN;

    const f16_t* A0 = A + (long)bz * sA;
    const f16_t* B0 = B + (long)bz * sB;

    const int tid  = threadIdx.x;
    const int lane = tid & 63;
    const int wid  = tid >> 6;
    const int wr   = wid >> 1;
    const int wc   = wid & 1;

    const int srow = tid >> 2;
    const int sgc  = (((tid & 3) ^ (srow & 3)) << 3);
    const int ldsb = wid * 512;

    const int fr  = lane & 15;
    const int kgs = (((lane >> 4) ^ (lane & 3)) << 3);

    f32x4 acc[4][4] = {};

    const long arow = (bm + srow) * (long)lda;
    const long brow = (bn + srow) * (long)ldb;

    for (int k0 = 0; k0 < K; k0 += BK) {
        const f16_t* a = A0 + arow + k0 + sgc;
        const f16_t* b = B0 + brow + k0 + sgc;
        gld_lds16(a,             &As[ldsb]);
        gld_lds16(a + 64L * lda, &As[2048 + ldsb]);
        gld_lds16(b,             &Bs[ldsb]);
        gld_lds16(b + 64L * ldb, &Bs[2048 + ldsb]);
        __syncthreads();

        f16x8 af[4], bg[4];
        #pragma unroll
        for (int m = 0; m < 4; ++m)
            af[m] = *(const f16x8*)&As[(wr * 64 + m * 16 + fr) * BK + kgs];
        #pragma unroll
        for (int n = 0; n < 4; ++n)
            bg[n] = *(const f16x8*)&Bs[(wc * 64 + n * 16 + fr) * BK + kgs];
        #pragma unroll
        for (int m = 0; m < 4; ++m)
            #pragma unroll
            for (int n = 0; n < 4; ++n)
                acc[m][n] = __builtin_amdgcn_mfma_f32_16x16x32_f16(
                    af[m], bg[n], acc[m][n], 0, 0, 0);
        __syncthreads();
    }

    const int rq = (lane >> 4) * 4;
    #pragma unroll
    for (int m = 0; m < 4; ++m) {
        #pragma unroll
        for (int n = 0; n < 4; ++n) {
            const long col = bn + wc * 64 + n * 16 + fr;
            #pragma unroll
            for (int r = 0; r < 4; ++r) {
                const long row = bm + wr * 64 + m * 16 + rq + r;
                const long idx = (long)bz * sC + row * ldc + col;
                const float v = acc[m][n][r];
                if constexpr (EPI == 0) ((float*)C0v)[idx] = v;
                else                    ((f16_t*)C0v)[idx] = (f16_t)v;
            }
        }
    }
}

// ==================== fused prep: cvt + split + transpose ===================
// regions (blockIdx.x): [0,8192) x-split; [8192,9216) Wq; [9216,10240) Wk;
// [10240,11264) Wo; [11264,11520) Wv transpose-cvt (64x64 tiles).
__global__ __launch_bounds__(256)
void prep(const float* __restrict__ x,  const float* __restrict__ Wq,
          const float* __restrict__ Wk, const float* __restrict__ Wo,
          const float* __restrict__ Wv,
          f16_t* __restrict__ xh, f16_t* __restrict__ xl,
          f16_t* __restrict__ wqk, f16_t* __restrict__ wo16,
          f16_t* __restrict__ wvT)
{
    const int bid = blockIdx.x;
    const int tid = threadIdx.x;
    if (bid < 8192) {                       // x -> xh + xl (split)
        const int i = (bid * 256 + tid) * 4;
        const f32x4 v = *(const f32x4*)&x[i];
        f16x4 h, l;
        #pragma unroll
        for (int j = 0; j < 4; ++j) {
            h[j] = (f16_t)v[j];
            l[j] = (f16_t)(v[j] - (float)h[j]);
        }
        *(f16x4*)&xh[i] = h;
        *(f16x4*)&xl[i] = l;
    } else if (bid < 11264) {               // plain weight cvt
        const float* src; f16_t* dst;
        if      (bid < 9216)  { src = Wq; dst = wqk;              }
        else if (bid < 10240) { src = Wk; dst = wqk + 1024 * 1024; }
        else                  { src = Wo; dst = wo16;             }
        const int lb = (bid < 9216) ? bid - 8192 : (bid < 10240 ? bid - 9216 : bid - 10240);
        const int i = (lb * 256 + tid) * 4;
        const f32x4 v = *(const f32x4*)&src[i];
        f16x4 h;
        #pragma unroll
        for (int j = 0; j < 4; ++j) h[j] = (f16_t)v[j];
        *(f16x4*)&dst[i] = h;
    } else {                                // Wv -> wvT (transpose + cvt)
        __shared__ float tile[64][65];
        const int b  = bid - 11264;         // 256 tiles: 16x16
        const int br = b >> 4, bc = b & 15;
        const int c  = tid & 63;
        #pragma unroll
        for (int j = 0; j < 16; ++j) {
            const int r = j * 4 + (tid >> 6);
            tile[r][c] = Wv[(br * 64 + r) * 1024 + bc * 64 + c];
        }
        __syncthreads();
        #pragma unroll
        for (int j = 0; j < 16; ++j) {
            const int r = j * 4 + (tid >> 6);  // transposed-row = orig col
            wvT[(bc * 64 + r) * 1024 + br * 64 + c] = (f16_t)tile[c][r];
        }
    }
}

// row softmax over 2048 cols; one 256-thread block per row; fp32 in, fp16 out
__global__ __launch_bounds__(256)
void softmax_rows(const float* __restrict__ Sc, f16_t* __restrict__ P)
{
    constexpr int NC = 2048;
    const int row = blockIdx.x;
    const int tid = threadIdx.x;
    const float* s = Sc + (size_t)row * NC;

    float v[8];
    *(f32x4*)&v[0] = *(const f32x4*)&s[tid * 8];
    *(f32x4*)&v[4] = *(const f32x4*)&s[tid * 8 + 4];

    float m = v[0];
    #pragma unroll
    for (int j = 1; j < 8; ++j) m = fmaxf(m, v[j]);
    #pragma unroll
    for (int off = 1; off < 64; off <<= 1) m = fmaxf(m, __shfl_xor(m, off));

    __shared__ float redm[4], reds[4];
    if ((tid & 63) == 0) redm[tid >> 6] = m;
    __syncthreads();
    m = fmaxf(fmaxf(redm[0], redm[1]), fmaxf(redm[2], redm[3]));

    float sum = 0.f;
    #pragma unroll
    for (int j = 0; j < 8; ++j) { v[j] = __expf(v[j] - m); sum += v[j]; }
    #pragma unroll
    for (int off = 1; off < 64; off <<= 1) sum += __shfl_xor(sum, off);
    if ((tid & 63) == 0) reds[tid >> 6] = sum;
    __syncthreads();
    sum = reds[0] + reds[1] + reds[2] + reds[3];

    const float inv = 1.0f / sum;
    f16x8 o;
    #pragma unroll
    for (int j = 0; j < 8; ++j) o[j] = (f16_t)(v[j] * inv);
    *(f16x8*)(P + (size_t)row * NC + tid * 8) = o;
}

// =========================== driver =========================================
extern "C" void kernel_launch(void* const* d_in, const int* in_sizes, int n_in,
                              void* d_out, int out_size, void* d_ws, size_t ws_size,
                              hipStream_t stream)
{
    const float* x  = (const float*)d_in[0];
    const float* Wq = (const float*)d_in[1];
    const float* Wk = (const float*)d_in[2];
    const float* Wv = (const float*)d_in[3];
    const float* Wo = (const float*)d_in[4];
    float* out = (float*)d_out;

    constexpr long H = 1024, S = 2048, B = 4, NT = B * S;

    // Workspace (peak 144 MB):
    //  [0,16)    xh fp16      -> later score fp32 [0,64)  (xh dead after uT)
    //  [64,68)   wqk fp16 [2048][1024]
    //  [68,70)   wo16  [70,72) wvT  [72,74) wvo
    //  [80,96)   qh fp16 ; [96,112) kh fp16   -> later P [80,112)
    //  [112,128) uT fp16 [1024][8192]
    //  [128,144) xl fp16
    char* ws = (char*)d_ws;
    const size_t MB = 1u << 20;
    f16_t* xh    = (f16_t*)(ws + 0);
    float* score = (float*)(ws + 0);
    f16_t* wqk   = (f16_t*)(ws + 64 * MB);
    f16_t* wo16  = (f16_t*)(ws + 68 * MB);
    f16_t* wvT   = (f16_t*)(ws + 70 * MB);
    f16_t* wvo   = (f16_t*)(ws + 72 * MB);
    f16_t* qh    = (f16_t*)(ws + 80 * MB);
    f16_t* kh    = (f16_t*)(ws + 96 * MB);   // = qh + 8388608 elems
    f16_t* P     = (f16_t*)(ws + 80 * MB);   // after score (qh/kh dead)
    f16_t* uT    = (f16_t*)(ws + 112 * MB);
    f16_t* xl    = (f16_t*)(ws + 128 * MB);

    // 1. fused conversions/splits/transpose
    prep<<<dim3(11520), dim3(256), 0, stream>>>(x, Wq, Wk, Wo, Wv,
                                                xh, xl, wqk, wo16, wvT);

    // 2. q,k projection: 2 segments, virtual K=2048, fp16 col-split epilogue
    gemm256<3><<<dim3(256), dim3(512), 0, stream>>>(
        xh, xl, xh, wqk, wqk, wqk, 32, (int)H, (int)H, 0L, 0L, 0L,
        qh, (int)H, 8, 256);

    // 3. Wvo[f][d] = sum_e Wo[f][e] Wv[e][d]   (tiny: 64 blocks)
    gemm_nt<1><<<dim3(64), dim3(256), 0, stream>>>(
        wo16, wvT, (int)H, (int)H, (int)H, 0L, 0L, 0L, wvo, (int)H, 8, 8);

    // 4. uT[f][t] = sum_d Wvo[f][d] x[t][d]   (old vproj shape)
    gemm_nt<1><<<dim3(512), dim3(256), 0, stream>>>(
        wvo, xh, (int)H, (int)H, (int)H, 0L, 0L, 0L, uT, (int)NT, 64, 8);

    // 5. score = q k^T, 1 segment, all 4 batches (fp32, unscaled)
    gemm256<0><<<dim3(256), dim3(512), 0, stream>>>(
        qh, qh, qh, kh, kh, kh, 16, (int)H, (int)H,
        S * H, S * H, S * S, score, (int)S, 8, 64);

    // 6. softmax rows
    softmax_rows<<<dim3(B * S), dim3(256), 0, stream>>>(score, P);

    // 7. out = P * uT-slice^T  (fp32 straight to d_out)
    gemm_nt<0><<<dim3(512), dim3(256), 0, stream>>>(
        P, uT, (int)S, (int)S, (int)NT, S * S, S, S * H, out, (int)H, 8, 16);
}

// Round 10
// 241.807 us; speedup vs baseline: 2.4240x; 1.0030x over previous
//
#include <hip/hip_runtime.h>
#include <stdint.h>

// ---------------------------------------------------------------------------
// Fused attention, fp32 I/O, MI355X (gfx950).
// All GEMMs: C = A * B^T (NT), fp16 MFMA, fp32 accumulate.
//   qkproj: 2 segments (xh*W + xl*W), virtual K=2048 -> q,k at ~fp32 grade
//   score : 1 segment  (qh*kh), K=1024
//   output chain folded: out = P*(x*(Wo*Wv)^T)^T  (Wvo precomputed, uT=Wvo*x^T,
//   PV writes fp32 out directly).
// gemm256 = round-7/8 PROVEN 8-phase structure (frozen: rounds 3,4,5,6,9 all
// failed to beat it; r9's 4-phase raced). prep vectorized to 8 elems/thread.
// ---------------------------------------------------------------------------

typedef _Float16 f16_t;
typedef _Float16 f16x8 __attribute__((ext_vector_type(8)));
typedef _Float16 f16x4 __attribute__((ext_vector_type(4)));
typedef float    f32x4 __attribute__((ext_vector_type(4)));
typedef uint32_t u32;

__device__ __forceinline__ void gld_lds16(const void* g, void* l) {
    __builtin_amdgcn_global_load_lds(
        (const __attribute__((address_space(1))) void*)g,
        (__attribute__((address_space(3))) void*)l, 16, 0, 0);
}

__device__ __forceinline__ f16x8 ld128(const void* p) {
    f16x8 r;
    const u32 a = (u32)(uintptr_t)(__attribute__((address_space(3))) const void*)p;
    asm volatile("ds_read_b128 %0, %1" : "=v"(r) : "v"(a));
    return r;
}

// ======================= 256^2 8-phase GEMM (K-segments) ====================
// EPI 0: fp32 -> C0[bz*sC + row*ldc + col]
// EPI 3: fp16 col-split: col<1024 -> C0[row*1024+col], col>=1024 ->
//        C0[8388608 + row*1024 + (col-1024)]  (adjacent 16MB buffer).
template<int EPI>
__global__ __launch_bounds__(512, 2)
void gemm256(const f16_t* __restrict__ A0, const f16_t* __restrict__ A1,
             const f16_t* __restrict__ A2,
             const f16_t* __restrict__ B0, const f16_t* __restrict__ B1,
             const f16_t* __restrict__ B2,
             int NK, int lda, int ldb, long sA, long sB, long sC,
             void* __restrict__ C0v, int ldc,
             int nbx, int plane)
{
    __shared__ __align__(1024) char smem[131072];

    const int nwg = (int)gridDim.x;
    int id = (int)blockIdx.x;
    id = (id & 7) * (nwg >> 3) + (id >> 3);
    const int bz  = id / plane;
    const int rem = id - bz * plane;
    const int by  = rem / nbx;
    const int bx  = rem - by * nbx;
    const long bm = (long)by * 256;
    const long bn = (long)bx * 256;
    const long zA = (long)bz * sA, zB = (long)bz * sB;

    const int tid  = threadIdx.x;
    const int lane = tid & 63;
    const int wid  = tid >> 6;
    const int wr   = wid >> 2;
    const int wc   = wid & 3;
    const int fr   = lane & 15;
    const int kg   = lane >> 4;

    const int srow = tid >> 3;
    const int scol = ((tid & 7) ^ ((tid >> 4) & 6)) << 3;
    const int ldsw = wid << 10;

    const int swzb    = (fr & 12) << 3;
    const int koff[2] = { (kg * 16) ^ swzb, (64 + kg * 16) ^ swzb };
    const int aBase   = wr * 16384 + fr * 128;
    const int bBase   = 32768 + (wc >> 1) * 16384 + (wc & 1) * 8192 + fr * 128;

    f32x4 acc[8][4] = {};
    f16x8 bfr[4][2];

    auto stage = [&](int kt, int part, int buf) {
        const int seg    = kt >> 4;
        const int klocal = (kt & 15) << 6;
        const bool isB = part < 2;
        const f16_t* base;
        if (isB) base = (seg == 0) ? B0 : (seg == 1 ? B1 : B2);
        else     base = (seg == 0) ? A0 : (seg == 1 ? A1 : A2);
        const long rowb = (isB ? (bn + part * 128) : (bm + (part - 2) * 128)) + srow;
        const long zoff = isB ? zB : zA;
        const int  ld   = isB ? ldb : lda;
        const int  poff = isB ? (32768 + part * 16384) : ((part - 2) * 16384);
        #pragma unroll
        for (int c = 0; c < 2; ++c) {
            const f16_t* g = base + zoff + (rowb + c * 64) * (long)ld + klocal + scol;
            gld_lds16(g, smem + buf * 65536 + poff + c * 8192 + ldsw);
        }
    };

    #pragma unroll
    for (int ht = 0; ht < 7; ++ht) stage(ht >> 2, ht & 3, (ht >> 2) & 1);
    asm volatile("s_waitcnt vmcnt(6)" ::: "memory");
    __builtin_amdgcn_s_barrier();

    const int NI = NK >> 1;
    #pragma unroll 1
    for (int i = 0; i < NI; ++i) {
        const bool last = (i == NI - 1);
        #pragma unroll
        for (int p = 0; p < 8; ++p) {
            const int q  = p & 3;
            const int cb = (p >> 2) * 65536;
            if (q == 0) {
                #pragma unroll
                for (int fn = 0; fn < 4; ++fn)
                    #pragma unroll
                    for (int kh = 0; kh < 2; ++kh)
                        bfr[fn][kh] = ld128(smem + cb + bBase
                                            + fn * 2048 + koff[kh]);
            }
            f16x8 afr[2][2];
            #pragma unroll
            for (int m2 = 0; m2 < 2; ++m2)
                #pragma unroll
                for (int kh = 0; kh < 2; ++kh)
                    afr[m2][kh] = ld128(smem + cb + aBase
                                        + (q * 2 + m2) * 2048 + koff[kh]);
            const int sc = (7 + p) >> 2;
            if (p == 0 || !last) stage(2 * i + sc, (7 + p) & 3, sc & 1);
            __builtin_amdgcn_sched_barrier(0);
            __builtin_amdgcn_s_barrier();
            asm volatile("s_waitcnt lgkmcnt(0)" ::: "memory");
            __builtin_amdgcn_sched_barrier(0);
            __builtin_amdgcn_s_setprio(1);
            #pragma unroll
            for (int m2 = 0; m2 < 2; ++m2)
                #pragma unroll
                for (int fn = 0; fn < 4; ++fn)
                    #pragma unroll
                    for (int kh = 0; kh < 2; ++kh)
                        acc[q * 2 + m2][fn] = __builtin_amdgcn_mfma_f32_16x16x32_f16(
                            afr[m2][kh], bfr[fn][kh], acc[q * 2 + m2][fn], 0, 0, 0);
            __builtin_amdgcn_s_setprio(0);
            __builtin_amdgcn_sched_barrier(0);
            if (q == 3) {
                if (last) asm volatile("s_waitcnt vmcnt(0)" ::: "memory");
                else      asm volatile("s_waitcnt vmcnt(6)" ::: "memory");
            }
            __builtin_amdgcn_s_barrier();
        }
    }

    const int rq = kg * 4;
    #pragma unroll
    for (int m = 0; m < 8; ++m) {
        #pragma unroll
        for (int fn = 0; fn < 4; ++fn) {
            const long col = bn + wc * 64 + fn * 16 + fr;
            #pragma unroll
            for (int r = 0; r < 4; ++r) {
                const long row = bm + wr * 128 + m * 16 + rq + r;
                const float v = acc[m][fn][r];
                if constexpr (EPI == 0) {
                    ((float*)C0v)[(long)bz * sC + row * ldc + col] = v;
                } else {
                    const long off = (col >= 1024)
                        ? 8388608L + row * 1024 + (col - 1024)
                        : row * 1024 + col;
                    ((f16_t*)C0v)[off] = (f16_t)v;
                }
            }
        }
    }
}

// ======================= 128^2 plain GEMM (proven) ==========================
#define BM 128
#define BN 128
#define BK 32

template<int EPI>   // 0 = fp32 C ; 1 = fp16 C
__global__ __launch_bounds__(256, 2)
void gemm_nt(const f16_t* __restrict__ A, const f16_t* __restrict__ B,
             int K, int lda, int ldb, long sA, long sB, long sC,
             void* __restrict__ C0v, int ldc, int nbx, int nby)
{
    __shared__ f16_t As[BM * BK];
    __shared__ f16_t Bs[BN * BK];

    const int nwg = (int)gridDim.x;
    int id = (int)blockIdx.x;
    id = (id & 7) * (nwg >> 3) + (id >> 3);
    const int plane = nbx * nby;
    const int bz  = id / plane;
    const int rem = id - bz * plane;
    const int by  = rem / nbx;
    const int bx  = rem - by * nbx;

    const long bm = (long)by * BM;
    const long bn = (long)bx * BN;

    const f16_t* A0 = A + (long)bz * sA;
    const f16_t* B0 = B + (long)bz * sB;

    const int tid  = threadIdx.x;
    const int lane = tid & 63;
    const int wid  = tid >> 6;
    const int wr   = wid >> 1;
    const int wc   = wid & 1;

    const int srow = tid >> 2;
    const int sgc  = (((tid & 3) ^ (srow & 3)) << 3);
    const int ldsb = wid * 512;

    const int fr  = lane & 15;
    const int kgs = (((lane >> 4) ^ (lane & 3)) << 3);

    f32x4 acc[4][4] = {};

    const long arow = (bm + srow) * (long)lda;
    const long brow = (bn + srow) * (long)ldb;

    for (int k0 = 0; k0 < K; k0 += BK) {
        const f16_t* a = A0 + arow + k0 + sgc;
        const f16_t* b = B0 + brow + k0 + sgc;
        gld_lds16(a,             &As[ldsb]);
        gld_lds16(a + 64L * lda, &As[2048 + ldsb]);
        gld_lds16(b,             &Bs[ldsb]);
        gld_lds16(b + 64L * ldb, &Bs[2048 + ldsb]);
        __syncthreads();

        f16x8 af[4], bg[4];
        #pragma unroll
        for (int m = 0; m < 4; ++m)
            af[m] = *(const f16x8*)&As[(wr * 64 + m * 16 + fr) * BK + kgs];
        #pragma unroll
        for (int n = 0; n < 4; ++n)
            bg[n] = *(const f16x8*)&Bs[(wc * 64 + n * 16 + fr) * BK + kgs];
        #pragma unroll
        for (int m = 0; m < 4; ++m)
            #pragma unroll
            for (int n = 0; n < 4; ++n)
                acc[m][n] = __builtin_amdgcn_mfma_f32_16x16x32_f16(
                    af[m], bg[n], acc[m][n], 0, 0, 0);
        __syncthreads();
    }

    const int rq = (lane >> 4) * 4;
    #pragma unroll
    for (int m = 0; m < 4; ++m) {
        #pragma unroll
        for (int n = 0; n < 4; ++n) {
            const long col = bn + wc * 64 + n * 16 + fr;
            #pragma unroll
            for (int r = 0; r < 4; ++r) {
                const long row = bm + wr * 64 + m * 16 + rq + r;
                const long idx = (long)bz * sC + row * ldc + col;
                const float v = acc[m][n][r];
                if constexpr (EPI == 0) ((float*)C0v)[idx] = v;
                else                    ((f16_t*)C0v)[idx] = (f16_t)v;
            }
        }
    }
}

// ==================== fused prep: cvt + split + transpose ===================
// 8 elems/thread. regions (blockIdx.x): [0,4096) x-split; [4096,4608) Wq;
// [4608,5120) Wk; [5120,5632) Wo; [5632,5888) Wv transpose-cvt (64x64 tiles).
__global__ __launch_bounds__(256)
void prep(const float* __restrict__ x,  const float* __restrict__ Wq,
          const float* __restrict__ Wk, const float* __restrict__ Wo,
          const float* __restrict__ Wv,
          f16_t* __restrict__ xh, f16_t* __restrict__ xl,
          f16_t* __restrict__ wqk, f16_t* __restrict__ wo16,
          f16_t* __restrict__ wvT)
{
    const int bid = blockIdx.x;
    const int tid = threadIdx.x;
    if (bid < 4096) {                       // x -> xh + xl (split), 8/thread
        const int i = (bid * 256 + tid) * 8;
        const f32x4 v0 = *(const f32x4*)&x[i];
        const f32x4 v1 = *(const f32x4*)&x[i + 4];
        f16x8 h, l;
        #pragma unroll
        for (int j = 0; j < 4; ++j) {
            h[j]     = (f16_t)v0[j];
            l[j]     = (f16_t)(v0[j] - (float)h[j]);
            h[j + 4] = (f16_t)v1[j];
            l[j + 4] = (f16_t)(v1[j] - (float)h[j + 4]);
        }
        *(f16x8*)&xh[i] = h;
        *(f16x8*)&xl[i] = l;
    } else if (bid < 5632) {                // plain weight cvt, 8/thread
        const float* src; f16_t* dst;
        if      (bid < 4608) { src = Wq; dst = wqk;               }
        else if (bid < 5120) { src = Wk; dst = wqk + 1024 * 1024; }
        else                 { src = Wo; dst = wo16;              }
        const int lb = (bid < 4608) ? bid - 4096 : (bid < 5120 ? bid - 4608 : bid - 5120);
        const int i = (lb * 256 + tid) * 8;
        const f32x4 v0 = *(const f32x4*)&src[i];
        const f32x4 v1 = *(const f32x4*)&src[i + 4];
        f16x8 h;
        #pragma unroll
        for (int j = 0; j < 4; ++j) {
            h[j]     = (f16_t)v0[j];
            h[j + 4] = (f16_t)v1[j];
        }
        *(f16x8*)&dst[i] = h;
    } else {                                // Wv -> wvT (transpose + cvt)
        __shared__ float tile[64][65];
        const int b  = bid - 5632;          // 256 tiles: 16x16
        const int br = b >> 4, bc = b & 15;
        const int c  = tid & 63;
        #pragma unroll
        for (int j = 0; j < 16; ++j) {
            const int r = j * 4 + (tid >> 6);
            tile[r][c] = Wv[(br * 64 + r) * 1024 + bc * 64 + c];
        }
        __syncthreads();
        #pragma unroll
        for (int j = 0; j < 16; ++j) {
            const int r = j * 4 + (tid >> 6);  // transposed-row = orig col
            wvT[(bc * 64 + r) * 1024 + br * 64 + c] = (f16_t)tile[c][r];
        }
    }
}

// row softmax over 2048 cols; one 256-thread block per row; fp32 in, fp16 out
__global__ __launch_bounds__(256)
void softmax_rows(const float* __restrict__ Sc, f16_t* __restrict__ P)
{
    constexpr int NC = 2048;
    const int row = blockIdx.x;
    const int tid = threadIdx.x;
    const float* s = Sc + (size_t)row * NC;

    float v[8];
    *(f32x4*)&v[0] = *(const f32x4*)&s[tid * 8];
    *(f32x4*)&v[4] = *(const f32x4*)&s[tid * 8 + 4];

    float m = v[0];
    #pragma unroll
    for (int j = 1; j < 8; ++j) m = fmaxf(m, v[j]);
    #pragma unroll
    for (int off = 1; off < 64; off <<= 1) m = fmaxf(m, __shfl_xor(m, off));

    __shared__ float redm[4], reds[4];
    if ((tid & 63) == 0) redm[tid >> 6] = m;
    __syncthreads();
    m = fmaxf(fmaxf(redm[0], redm[1]), fmaxf(redm[2], redm[3]));

    float sum = 0.f;
    #pragma unroll
    for (int j = 0; j < 8; ++j) { v[j] = __expf(v[j] - m); sum += v[j]; }
    #pragma unroll
    for (int off = 1; off < 64; off <<= 1) sum += __shfl_xor(sum, off);
    if ((tid & 63) == 0) reds[tid >> 6] = sum;
    __syncthreads();
    sum = reds[0] + reds[1] + reds[2] + reds[3];

    const float inv = 1.0f / sum;
    f16x8 o;
    #pragma unroll
    for (int j = 0; j < 8; ++j) o[j] = (f16_t)(v[j] * inv);
    *(f16x8*)(P + (size_t)row * NC + tid * 8) = o;
}

// =========================== driver =========================================
extern "C" void kernel_launch(void* const* d_in, const int* in_sizes, int n_in,
                              void* d_out, int out_size, void* d_ws, size_t ws_size,
                              hipStream_t stream)
{
    const float* x  = (const float*)d_in[0];
    const float* Wq = (const float*)d_in[1];
    const float* Wk = (const float*)d_in[2];
    const float* Wv = (const float*)d_in[3];
    const float* Wo = (const float*)d_in[4];
    float* out = (float*)d_out;

    constexpr long H = 1024, S = 2048, B = 4, NT = B * S;

    // Workspace (peak 144 MB):
    //  [0,16)    xh fp16      -> later score fp32 [0,64)  (xh dead after uT)
    //  [64,68)   wqk fp16 [2048][1024]
    //  [68,70)   wo16  [70,72) wvT  [72,74) wvo
    //  [80,96)   qh fp16 ; [96,112) kh fp16   -> later P [80,112)
    //  [112,128) uT fp16 [1024][8192]
    //  [128,144) xl fp16
    char* ws = (char*)d_ws;
    const size_t MB = 1u << 20;
    f16_t* xh    = (f16_t*)(ws + 0);
    float* score = (float*)(ws + 0);
    f16_t* wqk   = (f16_t*)(ws + 64 * MB);
    f16_t* wo16  = (f16_t*)(ws + 68 * MB);
    f16_t* wvT   = (f16_t*)(ws + 70 * MB);
    f16_t* wvo   = (f16_t*)(ws + 72 * MB);
    f16_t* qh    = (f16_t*)(ws + 80 * MB);
    f16_t* kh    = (f16_t*)(ws + 96 * MB);   // = qh + 8388608 elems
    f16_t* P     = (f16_t*)(ws + 80 * MB);   // after score (qh/kh dead)
    f16_t* uT    = (f16_t*)(ws + 112 * MB);
    f16_t* xl    = (f16_t*)(ws + 128 * MB);

    // 1. fused conversions/splits/transpose
    prep<<<dim3(5888), dim3(256), 0, stream>>>(x, Wq, Wk, Wo, Wv,
                                               xh, xl, wqk, wo16, wvT);

    // 2. q,k projection: 2 segments, virtual K=2048, fp16 col-split epilogue
    gemm256<3><<<dim3(256), dim3(512), 0, stream>>>(
        xh, xl, xh, wqk, wqk, wqk, 32, (int)H, (int)H, 0L, 0L, 0L,
        qh, (int)H, 8, 256);

    // 3. Wvo[f][d] = sum_e Wo[f][e] Wv[e][d]   (tiny: 64 blocks)
    gemm_nt<1><<<dim3(64), dim3(256), 0, stream>>>(
        wo16, wvT, (int)H, (int)H, (int)H, 0L, 0L, 0L, wvo, (int)H, 8, 8);

    // 4. uT[f][t] = sum_d Wvo[f][d] x[t][d]
    gemm_nt<1><<<dim3(512), dim3(256), 0, stream>>>(
        wvo, xh, (int)H, (int)H, (int)H, 0L, 0L, 0L, uT, (int)NT, 64, 8);

    // 5. score = q k^T, 1 segment, all 4 batches (fp32, unscaled)
    gemm256<0><<<dim3(256), dim3(512), 0, stream>>>(
        qh, qh, qh, kh, kh, kh, 16, (int)H, (int)H,
        S * H, S * H, S * S, score, (int)S, 8, 64);

    // 6. softmax rows
    softmax_rows<<<dim3(B * S), dim3(256), 0, stream>>>(score, P);

    // 7. out = P * uT-slice^T  (fp32 straight to d_out)
    gemm_nt<0><<<dim3(512), dim3(256), 0, stream>>>(
        P, uT, (int)S, (int)S, (int)NT, S * S, S, S * H, out, (int)H, 8, 16);
}

// Round 11
// 239.725 us; speedup vs baseline: 2.4451x; 1.0087x over previous
//
#include <hip/hip_runtime.h>
#include <stdint.h>

// ---------------------------------------------------------------------------
// Fused attention, fp32 I/O, MI355X (gfx950).
// All GEMMs: C = A * B^T (NT), fp16 MFMA, fp32 accumulate.
//   qkproj: 2 segments (xh*W + xl*W), virtual K=2048 -> q,k at ~fp32 grade
//   score : 1 segment  (qh*kh), K=1024
//   output chain folded: out = P*(x*(Wo*Wv)^T)^T  (Wvo precomputed, uT=Wvo*x^T,
//   PV writes fp32 out directly).
// gemm256 = frozen 8-phase structure. THIS ROUND: 3-bit LDS involution
// f(row)=(row&14)<<3 (was (row&12)<<3). Quarter-wave bank audit: 128B rows ->
// bank = col/4 mod 32 (row-independent); 16-lane service groups previously hit
// only 4 column slots (2 row bits in the XOR) = 4-way conflict = the measured
// 4.00 conflict-cycles/ds_read. 3 row bits -> 8 slots -> 2/bank (free, m136).
// Both sides updated consistently (staging source chunk + read offset).
// ---------------------------------------------------------------------------

typedef _Float16 f16_t;
typedef _Float16 f16x8 __attribute__((ext_vector_type(8)));
typedef _Float16 f16x4 __attribute__((ext_vector_type(4)));
typedef float    f32x4 __attribute__((ext_vector_type(4)));
typedef uint32_t u32;

__device__ __forceinline__ void gld_lds16(const void* g, void* l) {
    __builtin_amdgcn_global_load_lds(
        (const __attribute__((address_space(1))) void*)g,
        (__attribute__((address_space(3))) void*)l, 16, 0, 0);
}

__device__ __forceinline__ f16x8 ld128(const void* p) {
    f16x8 r;
    const u32 a = (u32)(uintptr_t)(__attribute__((address_space(3))) const void*)p;
    asm volatile("ds_read_b128 %0, %1" : "=v"(r) : "v"(a));
    return r;
}

// ======================= 256^2 8-phase GEMM (K-segments) ====================
// EPI 0: fp32 -> C0[bz*sC + row*ldc + col]
// EPI 3: fp16 col-split: col<1024 -> C0[row*1024+col], col>=1024 ->
//        C0[8388608 + row*1024 + (col-1024)]  (adjacent 16MB buffer).
template<int EPI>
__global__ __launch_bounds__(512, 2)
void gemm256(const f16_t* __restrict__ A0, const f16_t* __restrict__ A1,
             const f16_t* __restrict__ A2,
             const f16_t* __restrict__ B0, const f16_t* __restrict__ B1,
             const f16_t* __restrict__ B2,
             int NK, int lda, int ldb, long sA, long sB, long sC,
             void* __restrict__ C0v, int ldc,
             int nbx, int plane)
{
    __shared__ __align__(1024) char smem[131072];

    const int nwg = (int)gridDim.x;
    int id = (int)blockIdx.x;
    id = (id & 7) * (nwg >> 3) + (id >> 3);
    const int bz  = id / plane;
    const int rem = id - bz * plane;
    const int by  = rem / nbx;
    const int bx  = rem - by * nbx;
    const long bm = (long)by * 256;
    const long bn = (long)bx * 256;
    const long zA = (long)bz * sA, zB = (long)bz * sB;

    const int tid  = threadIdx.x;
    const int lane = tid & 63;
    const int wid  = tid >> 6;
    const int wr   = wid >> 2;
    const int wc   = wid & 3;
    const int fr   = lane & 15;
    const int kg   = lane >> 4;

    // staging: thread t covers chunk-row t>>3 (+64 via c), 16B chunk t&7, with
    // the 3-bit involution pre-applied to the GLOBAL source:
    // chunk ^= row-bits {1,2,3}  (srow bits 1-3 = tid bits 4-6).
    const int srow = tid >> 3;
    const int scol = ((tid & 7) ^ ((tid >> 4) & 7)) << 3;
    const int ldsw = wid << 10;

    // read-side: same involution on the column byte: colb ^= (row&14)<<3
    const int swzb    = (fr & 14) << 3;
    const int koff[2] = { (kg * 16) ^ swzb, (64 + kg * 16) ^ swzb };
    const int aBase   = wr * 16384 + fr * 128;
    const int bBase   = 32768 + (wc >> 1) * 16384 + (wc & 1) * 8192 + fr * 128;

    f32x4 acc[8][4] = {};
    f16x8 bfr[4][2];

    auto stage = [&](int kt, int part, int buf) {
        const int seg    = kt >> 4;
        const int klocal = (kt & 15) << 6;
        const bool isB = part < 2;
        const f16_t* base;
        if (isB) base = (seg == 0) ? B0 : (seg == 1 ? B1 : B2);
        else     base = (seg == 0) ? A0 : (seg == 1 ? A1 : A2);
        const long rowb = (isB ? (bn + part * 128) : (bm + (part - 2) * 128)) + srow;
        const long zoff = isB ? zB : zA;
        const int  ld   = isB ? ldb : lda;
        const int  poff = isB ? (32768 + part * 16384) : ((part - 2) * 16384);
        #pragma unroll
        for (int c = 0; c < 2; ++c) {
            const f16_t* g = base + zoff + (rowb + c * 64) * (long)ld + klocal + scol;
            gld_lds16(g, smem + buf * 65536 + poff + c * 8192 + ldsw);
        }
    };

    #pragma unroll
    for (int ht = 0; ht < 7; ++ht) stage(ht >> 2, ht & 3, (ht >> 2) & 1);
    asm volatile("s_waitcnt vmcnt(6)" ::: "memory");
    __builtin_amdgcn_s_barrier();

    const int NI = NK >> 1;
    #pragma unroll 1
    for (int i = 0; i < NI; ++i) {
        const bool last = (i == NI - 1);
        #pragma unroll
        for (int p = 0; p < 8; ++p) {
            const int q  = p & 3;
            const int cb = (p >> 2) * 65536;
            if (q == 0) {
                #pragma unroll
                for (int fn = 0; fn < 4; ++fn)
                    #pragma unroll
                    for (int kh = 0; kh < 2; ++kh)
                        bfr[fn][kh] = ld128(smem + cb + bBase
                                            + fn * 2048 + koff[kh]);
            }
            f16x8 afr[2][2];
            #pragma unroll
            for (int m2 = 0; m2 < 2; ++m2)
                #pragma unroll
                for (int kh = 0; kh < 2; ++kh)
                    afr[m2][kh] = ld128(smem + cb + aBase
                                        + (q * 2 + m2) * 2048 + koff[kh]);
            const int sc = (7 + p) >> 2;
            if (p == 0 || !last) stage(2 * i + sc, (7 + p) & 3, sc & 1);
            __builtin_amdgcn_sched_barrier(0);
            __builtin_amdgcn_s_barrier();
            asm volatile("s_waitcnt lgkmcnt(0)" ::: "memory");
            __builtin_amdgcn_sched_barrier(0);
            __builtin_amdgcn_s_setprio(1);
            #pragma unroll
            for (int m2 = 0; m2 < 2; ++m2)
                #pragma unroll
                for (int fn = 0; fn < 4; ++fn)
                    #pragma unroll
                    for (int kh = 0; kh < 2; ++kh)
                        acc[q * 2 + m2][fn] = __builtin_amdgcn_mfma_f32_16x16x32_f16(
                            afr[m2][kh], bfr[fn][kh], acc[q * 2 + m2][fn], 0, 0, 0);
            __builtin_amdgcn_s_setprio(0);
            __builtin_amdgcn_sched_barrier(0);
            if (q == 3) {
                if (last) asm volatile("s_waitcnt vmcnt(0)" ::: "memory");
                else      asm volatile("s_waitcnt vmcnt(6)" ::: "memory");
            }
            __builtin_amdgcn_s_barrier();
        }
    }

    const int rq = kg * 4;
    #pragma unroll
    for (int m = 0; m < 8; ++m) {
        #pragma unroll
        for (int fn = 0; fn < 4; ++fn) {
            const long col = bn + wc * 64 + fn * 16 + fr;
            #pragma unroll
            for (int r = 0; r < 4; ++r) {
                const long row = bm + wr * 128 + m * 16 + rq + r;
                const float v = acc[m][fn][r];
                if constexpr (EPI == 0) {
                    ((float*)C0v)[(long)bz * sC + row * ldc + col] = v;
                } else {
                    const long off = (col >= 1024)
                        ? 8388608L + row * 1024 + (col - 1024)
                        : row * 1024 + col;
                    ((f16_t*)C0v)[off] = (f16_t)v;
                }
            }
        }
    }
}

// ======================= 128^2 plain GEMM (proven) ==========================
#define BM 128
#define BN 128
#define BK 32

template<int EPI>   // 0 = fp32 C ; 1 = fp16 C
__global__ __launch_bounds__(256, 2)
void gemm_nt(const f16_t* __restrict__ A, const f16_t* __restrict__ B,
             int K, int lda, int ldb, long sA, long sB, long sC,
             void* __restrict__ C0v, int ldc, int nbx, int nby)
{
    __shared__ f16_t As[BM * BK];
    __shared__ f16_t Bs[BN * BK];

    const int nwg = (int)gridDim.x;
    int id = (int)blockIdx.x;
    id = (id & 7) * (nwg >> 3) + (id >> 3);
    const int plane = nbx * nby;
    const int bz  = id / plane;
    const int rem = id - bz * plane;
    const int by  = rem / nbx;
    const int bx  = rem - by * nbx;

    const long bm = (long)by * BM;
    const long bn = (long)bx * BN;

    const f16_t* A0 = A + (long)bz * sA;
    const f16_t* B0 = B + (long)bz * sB;

    const int tid  = threadIdx.x;
    const int lane = tid & 63;
    const int wid  = tid >> 6;
    const int wr   = wid >> 1;
    const int wc   = wid & 1;

    const int srow = tid >> 2;
    const int sgc  = (((tid & 3) ^ (srow & 3)) << 3);
    const int ldsb = wid * 512;

    const int fr  = lane & 15;
    const int kgs = (((lane >> 4) ^ (lane & 3)) << 3);

    f32x4 acc[4][4] = {};

    const long arow = (bm + srow) * (long)lda;
    const long brow = (bn + srow) * (long)ldb;

    for (int k0 = 0; k0 < K; k0 += BK) {
        const f16_t* a = A0 + arow + k0 + sgc;
        const f16_t* b = B0 + brow + k0 + sgc;
        gld_lds16(a,             &As[ldsb]);
        gld_lds16(a + 64L * lda, &As[2048 + ldsb]);
        gld_lds16(b,             &Bs[ldsb]);
        gld_lds16(b + 64L * ldb, &Bs[2048 + ldsb]);
        __syncthreads();

        f16x8 af[4], bg[4];
        #pragma unroll
        for (int m = 0; m < 4; ++m)
            af[m] = *(const f16x8*)&As[(wr * 64 + m * 16 + fr) * BK + kgs];
        #pragma unroll
        for (int n = 0; n < 4; ++n)
            bg[n] = *(const f16x8*)&Bs[(wc * 64 + n * 16 + fr) * BK + kgs];
        #pragma unroll
        for (int m = 0; m < 4; ++m)
            #pragma unroll
            for (int n = 0; n < 4; ++n)
                acc[m][n] = __builtin_amdgcn_mfma_f32_16x16x32_f16(
                    af[m], bg[n], acc[m][n], 0, 0, 0);
        __syncthreads();
    }

    const int rq = (lane >> 4) * 4;
    #pragma unroll
    for (int m = 0; m < 4; ++m) {
        #pragma unroll
        for (int n = 0; n < 4; ++n) {
            const long col = bn + wc * 64 + n * 16 + fr;
            #pragma unroll
            for (int r = 0; r < 4; ++r) {
                const long row = bm + wr * 64 + m * 16 + rq + r;
                const long idx = (long)bz * sC + row * ldc + col;
                const float v = acc[m][n][r];
                if constexpr (EPI == 0) ((float*)C0v)[idx] = v;
                else                    ((f16_t*)C0v)[idx] = (f16_t)v;
            }
        }
    }
}

// ==================== fused prep: cvt + split + transpose ===================
// 8 elems/thread. regions (blockIdx.x): [0,4096) x-split; [4096,4608) Wq;
// [4608,5120) Wk; [5120,5632) Wo; [5632,5888) Wv transpose-cvt (64x64 tiles).
__global__ __launch_bounds__(256)
void prep(const float* __restrict__ x,  const float* __restrict__ Wq,
          const float* __restrict__ Wk, const float* __restrict__ Wo,
          const float* __restrict__ Wv,
          f16_t* __restrict__ xh, f16_t* __restrict__ xl,
          f16_t* __restrict__ wqk, f16_t* __restrict__ wo16,
          f16_t* __restrict__ wvT)
{
    const int bid = blockIdx.x;
    const int tid = threadIdx.x;
    if (bid < 4096) {                       // x -> xh + xl (split), 8/thread
        const int i = (bid * 256 + tid) * 8;
        const f32x4 v0 = *(const f32x4*)&x[i];
        const f32x4 v1 = *(const f32x4*)&x[i + 4];
        f16x8 h, l;
        #pragma unroll
        for (int j = 0; j < 4; ++j) {
            h[j]     = (f16_t)v0[j];
            l[j]     = (f16_t)(v0[j] - (float)h[j]);
            h[j + 4] = (f16_t)v1[j];
            l[j + 4] = (f16_t)(v1[j] - (float)h[j + 4]);
        }
        *(f16x8*)&xh[i] = h;
        *(f16x8*)&xl[i] = l;
    } else if (bid < 5632) {                // plain weight cvt, 8/thread
        const float* src; f16_t* dst;
        if      (bid < 4608) { src = Wq; dst = wqk;               }
        else if (bid < 5120) { src = Wk; dst = wqk + 1024 * 1024; }
        else                 { src = Wo; dst = wo16;              }
        const int lb = (bid < 4608) ? bid - 4096 : (bid < 5120 ? bid - 4608 : bid - 5120);
        const int i = (lb * 256 + tid) * 8;
        const f32x4 v0 = *(const f32x4*)&src[i];
        const f32x4 v1 = *(const f32x4*)&src[i + 4];
        f16x8 h;
        #pragma unroll
        for (int j = 0; j < 4; ++j) {
            h[j]     = (f16_t)v0[j];
            h[j + 4] = (f16_t)v1[j];
        }
        *(f16x8*)&dst[i] = h;
    } else {                                // Wv -> wvT (transpose + cvt)
        __shared__ float tile[64][65];
        const int b  = bid - 5632;          // 256 tiles: 16x16
        const int br = b >> 4, bc = b & 15;
        const int c  = tid & 63;
        #pragma unroll
        for (int j = 0; j < 16; ++j) {
            const int r = j * 4 + (tid >> 6);
            tile[r][c] = Wv[(br * 64 + r) * 1024 + bc * 64 + c];
        }
        __syncthreads();
        #pragma unroll
        for (int j = 0; j < 16; ++j) {
            const int r = j * 4 + (tid >> 6);  // transposed-row = orig col
            wvT[(bc * 64 + r) * 1024 + br * 64 + c] = (f16_t)tile[c][r];
        }
    }
}

// row softmax over 2048 cols; one 256-thread block per row; fp32 in, fp16 out
__global__ __launch_bounds__(256)
void softmax_rows(const float* __restrict__ Sc, f16_t* __restrict__ P)
{
    constexpr int NC = 2048;
    const int row = blockIdx.x;
    const int tid = threadIdx.x;
    const float* s = Sc + (size_t)row * NC;

    float v[8];
    *(f32x4*)&v[0] = *(const f32x4*)&s[tid * 8];
    *(f32x4*)&v[4] = *(const f32x4*)&s[tid * 8 + 4];

    float m = v[0];
    #pragma unroll
    for (int j = 1; j < 8; ++j) m = fmaxf(m, v[j]);
    #pragma unroll
    for (int off = 1; off < 64; off <<= 1) m = fmaxf(m, __shfl_xor(m, off));

    __shared__ float redm[4], reds[4];
    if ((tid & 63) == 0) redm[tid >> 6] = m;
    __syncthreads();
    m = fmaxf(fmaxf(redm[0], redm[1]), fmaxf(redm[2], redm[3]));

    float sum = 0.f;
    #pragma unroll
    for (int j = 0; j < 8; ++j) { v[j] = __expf(v[j] - m); sum += v[j]; }
    #pragma unroll
    for (int off = 1; off < 64; off <<= 1) sum += __shfl_xor(sum, off);
    if ((tid & 63) == 0) reds[tid >> 6] = sum;
    __syncthreads();
    sum = reds[0] + reds[1] + reds[2] + reds[3];

    const float inv = 1.0f / sum;
    f16x8 o;
    #pragma unroll
    for (int j = 0; j < 8; ++j) o[j] = (f16_t)(v[j] * inv);
    *(f16x8*)(P + (size_t)row * NC + tid * 8) = o;
}

// =========================== driver =========================================
extern "C" void kernel_launch(void* const* d_in, const int* in_sizes, int n_in,
                              void* d_out, int out_size, void* d_ws, size_t ws_size,
                              hipStream_t stream)
{
    const float* x  = (const float*)d_in[0];
    const float* Wq = (const float*)d_in[1];
    const float* Wk = (const float*)d_in[2];
    const float* Wv = (const float*)d_in[3];
    const float* Wo = (const float*)d_in[4];
    float* out = (float*)d_out;

    constexpr long H = 1024, S = 2048, B = 4, NT = B * S;

    // Workspace (peak 144 MB):
    //  [0,16)    xh fp16      -> later score fp32 [0,64)  (xh dead after uT)
    //  [64,68)   wqk fp16 [2048][1024]
    //  [68,70)   wo16  [70,72) wvT  [72,74) wvo
    //  [80,96)   qh fp16 ; [96,112) kh fp16   -> later P [80,112)
    //  [112,128) uT fp16 [1024][8192]
    //  [128,144) xl fp16
    char* ws = (char*)d_ws;
    const size_t MB = 1u << 20;
    f16_t* xh    = (f16_t*)(ws + 0);
    float* score = (float*)(ws + 0);
    f16_t* wqk   = (f16_t*)(ws + 64 * MB);
    f16_t* wo16  = (f16_t*)(ws + 68 * MB);
    f16_t* wvT   = (f16_t*)(ws + 70 * MB);
    f16_t* wvo   = (f16_t*)(ws + 72 * MB);
    f16_t* qh    = (f16_t*)(ws + 80 * MB);
    f16_t* kh    = (f16_t*)(ws + 96 * MB);   // = qh + 8388608 elems
    f16_t* P     = (f16_t*)(ws + 80 * MB);   // after score (qh/kh dead)
    f16_t* uT    = (f16_t*)(ws + 112 * MB);
    f16_t* xl    = (f16_t*)(ws + 128 * MB);

    // 1. fused conversions/splits/transpose
    prep<<<dim3(5888), dim3(256), 0, stream>>>(x, Wq, Wk, Wo, Wv,
                                               xh, xl, wqk, wo16, wvT);

    // 2. q,k projection: 2 segments, virtual K=2048, fp16 col-split epilogue
    gemm256<3><<<dim3(256), dim3(512), 0, stream>>>(
        xh, xl, xh, wqk, wqk, wqk, 32, (int)H, (int)H, 0L, 0L, 0L,
        qh, (int)H, 8, 256);

    // 3. Wvo[f][d] = sum_e Wo[f][e] Wv[e][d]   (tiny: 64 blocks)
    gemm_nt<1><<<dim3(64), dim3(256), 0, stream>>>(
        wo16, wvT, (int)H, (int)H, (int)H, 0L, 0L, 0L, wvo, (int)H, 8, 8);

    // 4. uT[f][t] = sum_d Wvo[f][d] x[t][d]
    gemm_nt<1><<<dim3(512), dim3(256), 0, stream>>>(
        wvo, xh, (int)H, (int)H, (int)H, 0L, 0L, 0L, uT, (int)NT, 64, 8);

    // 5. score = q k^T, 1 segment, all 4 batches (fp32, unscaled)
    gemm256<0><<<dim3(256), dim3(512), 0, stream>>>(
        qh, qh, qh, kh, kh, kh, 16, (int)H, (int)H,
        S * H, S * H, S * S, score, (int)S, 8, 64);

    // 6. softmax rows
    softmax_rows<<<dim3(B * S), dim3(256), 0, stream>>>(score, P);

    // 7. out = P * uT-slice^T  (fp32 straight to d_out)
    gemm_nt<0><<<dim3(512), dim3(256), 0, stream>>>(
        P, uT, (int)S, (int)S, (int)NT, S * S, S, S * H, out, (int)H, 8, 16);
}

// Round 12
// 236.378 us; speedup vs baseline: 2.4797x; 1.0142x over previous
//
#include <hip/hip_runtime.h>
#include <stdint.h>

// ---------------------------------------------------------------------------
// Fused attention, fp32 I/O, MI355X (gfx950).
// All GEMMs: C = A * B^T (NT), fp16 MFMA, fp32 accumulate.
//   qkproj: 2 segments (xh*W + xl*W), virtual K=2048 -> q,k at ~fp32 grade
//   score : 1 segment  (qh*kh), K=1024
//   output chain folded: out = P*(x*(Wo*Wv)^T)^T  (Wvo precomputed, uT=Wvo*x^T,
//   PV writes fp32 out directly).
// gemm256: frozen 8-phase structure + conflict-free 3-bit involution (r11,
// SQ_LDS_BANK_CONFLICT = 0). This round: removed 2 over-constraining
// sched_barrier(0) fences (kept rule-18 one), launch_bounds (512,1).
// gemm_nt: swizzle upgraded to chunk ^= (row>>1)&3 (4-way -> 2-way free).
// ---------------------------------------------------------------------------

typedef _Float16 f16_t;
typedef _Float16 f16x8 __attribute__((ext_vector_type(8)));
typedef _Float16 f16x4 __attribute__((ext_vector_type(4)));
typedef float    f32x4 __attribute__((ext_vector_type(4)));
typedef uint32_t u32;

__device__ __forceinline__ void gld_lds16(const void* g, void* l) {
    __builtin_amdgcn_global_load_lds(
        (const __attribute__((address_space(1))) void*)g,
        (__attribute__((address_space(3))) void*)l, 16, 0, 0);
}

__device__ __forceinline__ f16x8 ld128(const void* p) {
    f16x8 r;
    const u32 a = (u32)(uintptr_t)(__attribute__((address_space(3))) const void*)p;
    asm volatile("ds_read_b128 %0, %1" : "=v"(r) : "v"(a));
    return r;
}

// ======================= 256^2 8-phase GEMM (K-segments) ====================
// EPI 0: fp32 -> C0[bz*sC + row*ldc + col]
// EPI 3: fp16 col-split: col<1024 -> C0[row*1024+col], col>=1024 ->
//        C0[8388608 + row*1024 + (col-1024)]  (adjacent 16MB buffer).
template<int EPI>
__global__ __launch_bounds__(512, 1)
void gemm256(const f16_t* __restrict__ A0, const f16_t* __restrict__ A1,
             const f16_t* __restrict__ A2,
             const f16_t* __restrict__ B0, const f16_t* __restrict__ B1,
             const f16_t* __restrict__ B2,
             int NK, int lda, int ldb, long sA, long sB, long sC,
             void* __restrict__ C0v, int ldc,
             int nbx, int plane)
{
    __shared__ __align__(1024) char smem[131072];

    const int nwg = (int)gridDim.x;
    int id = (int)blockIdx.x;
    id = (id & 7) * (nwg >> 3) + (id >> 3);
    const int bz  = id / plane;
    const int rem = id - bz * plane;
    const int by  = rem / nbx;
    const int bx  = rem - by * nbx;
    const long bm = (long)by * 256;
    const long bn = (long)bx * 256;
    const long zA = (long)bz * sA, zB = (long)bz * sB;

    const int tid  = threadIdx.x;
    const int lane = tid & 63;
    const int wid  = tid >> 6;
    const int wr   = wid >> 2;
    const int wc   = wid & 3;
    const int fr   = lane & 15;
    const int kg   = lane >> 4;

    // staging: 3-bit involution pre-applied to the GLOBAL source:
    // chunk ^= row-bits {1,2,3}  (srow bits 1-3 = tid bits 4-6).
    const int srow = tid >> 3;
    const int scol = ((tid & 7) ^ ((tid >> 4) & 7)) << 3;
    const int ldsw = wid << 10;

    // read-side: same involution on the column byte: colb ^= (row&14)<<3
    const int swzb    = (fr & 14) << 3;
    const int koff[2] = { (kg * 16) ^ swzb, (64 + kg * 16) ^ swzb };
    const int aBase   = wr * 16384 + fr * 128;
    const int bBase   = 32768 + (wc >> 1) * 16384 + (wc & 1) * 8192 + fr * 128;

    f32x4 acc[8][4] = {};
    f16x8 bfr[4][2];

    auto stage = [&](int kt, int part, int buf) {
        const int seg    = kt >> 4;
        const int klocal = (kt & 15) << 6;
        const bool isB = part < 2;
        const f16_t* base;
        if (isB) base = (seg == 0) ? B0 : (seg == 1 ? B1 : B2);
        else     base = (seg == 0) ? A0 : (seg == 1 ? A1 : A2);
        const long rowb = (isB ? (bn + part * 128) : (bm + (part - 2) * 128)) + srow;
        const long zoff = isB ? zB : zA;
        const int  ld   = isB ? ldb : lda;
        const int  poff = isB ? (32768 + part * 16384) : ((part - 2) * 16384);
        #pragma unroll
        for (int c = 0; c < 2; ++c) {
            const f16_t* g = base + zoff + (rowb + c * 64) * (long)ld + klocal + scol;
            gld_lds16(g, smem + buf * 65536 + poff + c * 8192 + ldsw);
        }
    };

    #pragma unroll
    for (int ht = 0; ht < 7; ++ht) stage(ht >> 2, ht & 3, (ht >> 2) & 1);
    asm volatile("s_waitcnt vmcnt(6)" ::: "memory");
    __builtin_amdgcn_s_barrier();

    const int NI = NK >> 1;
    #pragma unroll 1
    for (int i = 0; i < NI; ++i) {
        const bool last = (i == NI - 1);
        #pragma unroll
        for (int p = 0; p < 8; ++p) {
            const int q  = p & 3;
            const int cb = (p >> 2) * 65536;
            if (q == 0) {
                #pragma unroll
                for (int fn = 0; fn < 4; ++fn)
                    #pragma unroll
                    for (int kh = 0; kh < 2; ++kh)
                        bfr[fn][kh] = ld128(smem + cb + bBase
                                            + fn * 2048 + koff[kh]);
            }
            f16x8 afr[2][2];
            #pragma unroll
            for (int m2 = 0; m2 < 2; ++m2)
                #pragma unroll
                for (int kh = 0; kh < 2; ++kh)
                    afr[m2][kh] = ld128(smem + cb + aBase
                                        + (q * 2 + m2) * 2048 + koff[kh]);
            const int sc = (7 + p) >> 2;
            if (p == 0 || !last) stage(2 * i + sc, (7 + p) & 3, sc & 1);
            __builtin_amdgcn_s_barrier();
            asm volatile("s_waitcnt lgkmcnt(0)" ::: "memory");
            __builtin_amdgcn_sched_barrier(0);   // rule #18: pin MFMA below wait
            __builtin_amdgcn_s_setprio(1);
            #pragma unroll
            for (int m2 = 0; m2 < 2; ++m2)
                #pragma unroll
                for (int fn = 0; fn < 4; ++fn)
                    #pragma unroll
                    for (int kh = 0; kh < 2; ++kh)
                        acc[q * 2 + m2][fn] = __builtin_amdgcn_mfma_f32_16x16x32_f16(
                            afr[m2][kh], bfr[fn][kh], acc[q * 2 + m2][fn], 0, 0, 0);
            __builtin_amdgcn_s_setprio(0);
            if (q == 3) {
                if (last) asm volatile("s_waitcnt vmcnt(0)" ::: "memory");
                else      asm volatile("s_waitcnt vmcnt(6)" ::: "memory");
            }
            __builtin_amdgcn_s_barrier();
        }
    }

    const int rq = kg * 4;
    #pragma unroll
    for (int m = 0; m < 8; ++m) {
        #pragma unroll
        for (int fn = 0; fn < 4; ++fn) {
            const long col = bn + wc * 64 + fn * 16 + fr;
            #pragma unroll
            for (int r = 0; r < 4; ++r) {
                const long row = bm + wr * 128 + m * 16 + rq + r;
                const float v = acc[m][fn][r];
                if constexpr (EPI == 0) {
                    ((float*)C0v)[(long)bz * sC + row * ldc + col] = v;
                } else {
                    const long off = (col >= 1024)
                        ? 8388608L + row * 1024 + (col - 1024)
                        : row * 1024 + col;
                    ((f16_t*)C0v)[off] = (f16_t)v;
                }
            }
        }
    }
}

// ======================= 128^2 plain GEMM (proven) ==========================
#define BM 128
#define BN 128
#define BK 32

template<int EPI>   // 0 = fp32 C ; 1 = fp16 C
__global__ __launch_bounds__(256, 2)
void gemm_nt(const f16_t* __restrict__ A, const f16_t* __restrict__ B,
             int K, int lda, int ldb, long sA, long sB, long sC,
             void* __restrict__ C0v, int ldc, int nbx, int nby)
{
    __shared__ f16_t As[BM * BK];
    __shared__ f16_t Bs[BN * BK];

    const int nwg = (int)gridDim.x;
    int id = (int)blockIdx.x;
    id = (id & 7) * (nwg >> 3) + (id >> 3);
    const int plane = nbx * nby;
    const int bz  = id / plane;
    const int rem = id - bz * plane;
    const int by  = rem / nbx;
    const int bx  = rem - by * nbx;

    const long bm = (long)by * BM;
    const long bn = (long)bx * BN;

    const f16_t* A0 = A + (long)bz * sA;
    const f16_t* B0 = B + (long)bz * sB;

    const int tid  = threadIdx.x;
    const int lane = tid & 63;
    const int wid  = tid >> 6;
    const int wr   = wid >> 1;
    const int wc   = wid & 1;

    // staging: chunk (tid&3) XOR row bits {1,2}  (srow=tid>>2 -> bits at tid 3,4)
    const int srow = tid >> 2;
    const int sgc  = (((tid & 3) ^ ((tid >> 3) & 3)) << 3);
    const int ldsb = wid * 512;

    // read: slot = chunk ^ ((row>>1)&3); row bits 1,2 = lane bits 1,2.
    // bank audit (64B rows, 16 banks/row): bank=(row*16+slot*16B)/4 mod 32 ->
    // quarter-wave covers rows 0-15 over banks with exactly 2 lanes/bank (free).
    const int fr  = lane & 15;
    const int kgs = (((lane >> 4) ^ ((lane >> 1) & 3)) << 3);

    f32x4 acc[4][4] = {};

    const long arow = (bm + srow) * (long)lda;
    const long brow = (bn + srow) * (long)ldb;

    for (int k0 = 0; k0 < K; k0 += BK) {
        const f16_t* a = A0 + arow + k0 + sgc;
        const f16_t* b = B0 + brow + k0 + sgc;
        gld_lds16(a,             &As[ldsb]);
        gld_lds16(a + 64L * lda, &As[2048 + ldsb]);
        gld_lds16(b,             &Bs[ldsb]);
        gld_lds16(b + 64L * ldb, &Bs[2048 + ldsb]);
        __syncthreads();

        f16x8 af[4], bg[4];
        #pragma unroll
        for (int m = 0; m < 4; ++m)
            af[m] = *(const f16x8*)&As[(wr * 64 + m * 16 + fr) * BK + kgs];
        #pragma unroll
        for (int n = 0; n < 4; ++n)
            bg[n] = *(const f16x8*)&Bs[(wc * 64 + n * 16 + fr) * BK + kgs];
        #pragma unroll
        for (int m = 0; m < 4; ++m)
            #pragma unroll
            for (int n = 0; n < 4; ++n)
                acc[m][n] = __builtin_amdgcn_mfma_f32_16x16x32_f16(
                    af[m], bg[n], acc[m][n], 0, 0, 0);
        __syncthreads();
    }

    const int rq = (lane >> 4) * 4;
    #pragma unroll
    for (int m = 0; m < 4; ++m) {
        #pragma unroll
        for (int n = 0; n < 4; ++n) {
            const long col = bn + wc * 64 + n * 16 + fr;
            #pragma unroll
            for (int r = 0; r < 4; ++r) {
                const long row = bm + wr * 64 + m * 16 + rq + r;
                const long idx = (long)bz * sC + row * ldc + col;
                const float v = acc[m][n][r];
                if constexpr (EPI == 0) ((float*)C0v)[idx] = v;
                else                    ((f16_t*)C0v)[idx] = (f16_t)v;
            }
        }
    }
}

// ==================== fused prep: cvt + split + transpose ===================
// 8 elems/thread. regions (blockIdx.x): [0,4096) x-split; [4096,4608) Wq;
// [4608,5120) Wk; [5120,5632) Wo; [5632,5888) Wv transpose-cvt (64x64 tiles).
__global__ __launch_bounds__(256)
void prep(const float* __restrict__ x,  const float* __restrict__ Wq,
          const float* __restrict__ Wk, const float* __restrict__ Wo,
          const float* __restrict__ Wv,
          f16_t* __restrict__ xh, f16_t* __restrict__ xl,
          f16_t* __restrict__ wqk, f16_t* __restrict__ wo16,
          f16_t* __restrict__ wvT)
{
    const int bid = blockIdx.x;
    const int tid = threadIdx.x;
    if (bid < 4096) {                       // x -> xh + xl (split), 8/thread
        const int i = (bid * 256 + tid) * 8;
        const f32x4 v0 = *(const f32x4*)&x[i];
        const f32x4 v1 = *(const f32x4*)&x[i + 4];
        f16x8 h, l;
        #pragma unroll
        for (int j = 0; j < 4; ++j) {
            h[j]     = (f16_t)v0[j];
            l[j]     = (f16_t)(v0[j] - (float)h[j]);
            h[j + 4] = (f16_t)v1[j];
            l[j + 4] = (f16_t)(v1[j] - (float)h[j + 4]);
        }
        *(f16x8*)&xh[i] = h;
        *(f16x8*)&xl[i] = l;
    } else if (bid < 5632) {                // plain weight cvt, 8/thread
        const float* src; f16_t* dst;
        if      (bid < 4608) { src = Wq; dst = wqk;               }
        else if (bid < 5120) { src = Wk; dst = wqk + 1024 * 1024; }
        else                 { src = Wo; dst = wo16;              }
        const int lb = (bid < 4608) ? bid - 4096 : (bid < 5120 ? bid - 4608 : bid - 5120);
        const int i = (lb * 256 + tid) * 8;
        const f32x4 v0 = *(const f32x4*)&src[i];
        const f32x4 v1 = *(const f32x4*)&src[i + 4];
        f16x8 h;
        #pragma unroll
        for (int j = 0; j < 4; ++j) {
            h[j]     = (f16_t)v0[j];
            h[j + 4] = (f16_t)v1[j];
        }
        *(f16x8*)&dst[i] = h;
    } else {                                // Wv -> wvT (transpose + cvt)
        __shared__ float tile[64][65];
        const int b  = bid - 5632;          // 256 tiles: 16x16
        const int br = b >> 4, bc = b & 15;
        const int c  = tid & 63;
        #pragma unroll
        for (int j = 0; j < 16; ++j) {
            const int r = j * 4 + (tid >> 6);
            tile[r][c] = Wv[(br * 64 + r) * 1024 + bc * 64 + c];
        }
        __syncthreads();
        #pragma unroll
        for (int j = 0; j < 16; ++j) {
            const int r = j * 4 + (tid >> 6);  // transposed-row = orig col
            wvT[(bc * 64 + r) * 1024 + br * 64 + c] = (f16_t)tile[c][r];
        }
    }
}

// row softmax over 2048 cols; one 256-thread block per row; fp32 in, fp16 out
__global__ __launch_bounds__(256)
void softmax_rows(const float* __restrict__ Sc, f16_t* __restrict__ P)
{
    constexpr int NC = 2048;
    const int row = blockIdx.x;
    const int tid = threadIdx.x;
    const float* s = Sc + (size_t)row * NC;

    float v[8];
    *(f32x4*)&v[0] = *(const f32x4*)&s[tid * 8];
    *(f32x4*)&v[4] = *(const f32x4*)&s[tid * 8 + 4];

    float m = v[0];
    #pragma unroll
    for (int j = 1; j < 8; ++j) m = fmaxf(m, v[j]);
    #pragma unroll
    for (int off = 1; off < 64; off <<= 1) m = fmaxf(m, __shfl_xor(m, off));

    __shared__ float redm[4], reds[4];
    if ((tid & 63) == 0) redm[tid >> 6] = m;
    __syncthreads();
    m = fmaxf(fmaxf(redm[0], redm[1]), fmaxf(redm[2], redm[3]));

    float sum = 0.f;
    #pragma unroll
    for (int j = 0; j < 8; ++j) { v[j] = __expf(v[j] - m); sum += v[j]; }
    #pragma unroll
    for (int off = 1; off < 64; off <<= 1) sum += __shfl_xor(sum, off);
    if ((tid & 63) == 0) reds[tid >> 6] = sum;
    __syncthreads();
    sum = reds[0] + reds[1] + reds[2] + reds[3];

    const float inv = 1.0f / sum;
    f16x8 o;
    #pragma unroll
    for (int j = 0; j < 8; ++j) o[j] = (f16_t)(v[j] * inv);
    *(f16x8*)(P + (size_t)row * NC + tid * 8) = o;
}

// =========================== driver =========================================
extern "C" void kernel_launch(void* const* d_in, const int* in_sizes, int n_in,
                              void* d_out, int out_size, void* d_ws, size_t ws_size,
                              hipStream_t stream)
{
    const float* x  = (const float*)d_in[0];
    const float* Wq = (const float*)d_in[1];
    const float* Wk = (const float*)d_in[2];
    const float* Wv = (const float*)d_in[3];
    const float* Wo = (const float*)d_in[4];
    float* out = (float*)d_out;

    constexpr long H = 1024, S = 2048, B = 4, NT = B * S;

    // Workspace (peak 144 MB):
    //  [0,16)    xh fp16      -> later score fp32 [0,64)  (xh dead after uT)
    //  [64,68)   wqk fp16 [2048][1024]
    //  [68,70)   wo16  [70,72) wvT  [72,74) wvo
    //  [80,96)   qh fp16 ; [96,112) kh fp16   -> later P [80,112)
    //  [112,128) uT fp16 [1024][8192]
    //  [128,144) xl fp16
    char* ws = (char*)d_ws;
    const size_t MB = 1u << 20;
    f16_t* xh    = (f16_t*)(ws + 0);
    float* score = (float*)(ws + 0);
    f16_t* wqk   = (f16_t*)(ws + 64 * MB);
    f16_t* wo16  = (f16_t*)(ws + 68 * MB);
    f16_t* wvT   = (f16_t*)(ws + 70 * MB);
    f16_t* wvo   = (f16_t*)(ws + 72 * MB);
    f16_t* qh    = (f16_t*)(ws + 80 * MB);
    f16_t* kh    = (f16_t*)(ws + 96 * MB);   // = qh + 8388608 elems
    f16_t* P     = (f16_t*)(ws + 80 * MB);   // after score (qh/kh dead)
    f16_t* uT    = (f16_t*)(ws + 112 * MB);
    f16_t* xl    = (f16_t*)(ws + 128 * MB);

    // 1. fused conversions/splits/transpose
    prep<<<dim3(5888), dim3(256), 0, stream>>>(x, Wq, Wk, Wo, Wv,
                                               xh, xl, wqk, wo16, wvT);

    // 2. q,k projection: 2 segments, virtual K=2048, fp16 col-split epilogue
    gemm256<3><<<dim3(256), dim3(512), 0, stream>>>(
        xh, xl, xh, wqk, wqk, wqk, 32, (int)H, (int)H, 0L, 0L, 0L,
        qh, (int)H, 8, 256);

    // 3. Wvo[f][d] = sum_e Wo[f][e] Wv[e][d]   (tiny: 64 blocks)
    gemm_nt<1><<<dim3(64), dim3(256), 0, stream>>>(
        wo16, wvT, (int)H, (int)H, (int)H, 0L, 0L, 0L, wvo, (int)H, 8, 8);

    // 4. uT[f][t] = sum_d Wvo[f][d] x[t][d]
    gemm_nt<1><<<dim3(512), dim3(256), 0, stream>>>(
        wvo, xh, (int)H, (int)H, (int)H, 0L, 0L, 0L, uT, (int)NT, 64, 8);

    // 5. score = q k^T, 1 segment, all 4 batches (fp32, unscaled)
    gemm256<0><<<dim3(256), dim3(512), 0, stream>>>(
        qh, qh, qh, kh, kh, kh, 16, (int)H, (int)H,
        S * H, S * H, S * S, score, (int)S, 8, 64);

    // 6. softmax rows
    softmax_rows<<<dim3(B * S), dim3(256), 0, stream>>>(score, P);

    // 7. out = P * uT-slice^T  (fp32 straight to d_out)
    gemm_nt<0><<<dim3(512), dim3(256), 0, stream>>>(
        P, uT, (int)S, (int)S, (int)NT, S * S, S, S * H, out, (int)H, 8, 16);
}

// Round 13
// 228.823 us; speedup vs baseline: 2.5616x; 1.0330x over previous
//
#include <hip/hip_runtime.h>
#include <stdint.h>

// ---------------------------------------------------------------------------
// Fused attention, fp32 I/O, MI355X (gfx950).
// All GEMMs: C = A * B^T (NT), fp16 MFMA, fp32 accumulate.
//   qkproj: 2 segments (xh*W + xl*W), virtual K=2048 -> q,k at ~fp32 grade
//   score : 1 segment  (qh*kh), K=1024
//   output chain folded: out = P*(x*(Wo*Wv)^T)^T  (Wvo precomputed, uT=Wvo*x^T,
//   PV writes fp32 out directly).
// gemm256 (qkproj, score): frozen 8-phase structure, conflict-free involution.
// NEW gemm128x256 (uT, PV): same engine at 128x256xBK64 tile -> 256-block
// grids (1 block/CU, full machine). 3 parts/K-tile staging schedule:
//   q0: stage T+1.A (other buf; its A-region free since T-1.q3 barrier)
//   q1: stage T+2.B0, q2: stage T+2.B1 (same buf; B-region free after T.q0)
//   drain: prologue vmcnt(4); per-tile q3 vmcnt(4) (T+1's 6 gld always older
//   than the <=4 outstanding); vmcnt(0) for last two tiles.
// Accumulation order k-ascending per acc element -> outputs bit-identical to
// the gemm_nt versions they replace (absmax must stay exactly 0.08203125).
// ---------------------------------------------------------------------------

typedef _Float16 f16_t;
typedef _Float16 f16x8 __attribute__((ext_vector_type(8)));
typedef _Float16 f16x4 __attribute__((ext_vector_type(4)));
typedef float    f32x4 __attribute__((ext_vector_type(4)));
typedef uint32_t u32;

__device__ __forceinline__ void gld_lds16(const void* g, void* l) {
    __builtin_amdgcn_global_load_lds(
        (const __attribute__((address_space(1))) void*)g,
        (__attribute__((address_space(3))) void*)l, 16, 0, 0);
}

__device__ __forceinline__ f16x8 ld128(const void* p) {
    f16x8 r;
    const u32 a = (u32)(uintptr_t)(__attribute__((address_space(3))) const void*)p;
    asm volatile("ds_read_b128 %0, %1" : "=v"(r) : "v"(a));
    return r;
}

// ======================= 256^2 8-phase GEMM (K-segments) ====================
// EPI 0: fp32 -> C0[bz*sC + row*ldc + col]
// EPI 3: fp16 col-split: col<1024 -> C0[row*1024+col], col>=1024 ->
//        C0[8388608 + row*1024 + (col-1024)]  (adjacent 16MB buffer).
template<int EPI>
__global__ __launch_bounds__(512, 1)
void gemm256(const f16_t* __restrict__ A0, const f16_t* __restrict__ A1,
             const f16_t* __restrict__ A2,
             const f16_t* __restrict__ B0, const f16_t* __restrict__ B1,
             const f16_t* __restrict__ B2,
             int NK, int lda, int ldb, long sA, long sB, long sC,
             void* __restrict__ C0v, int ldc,
             int nbx, int plane)
{
    __shared__ __align__(1024) char smem[131072];

    const int nwg = (int)gridDim.x;
    int id = (int)blockIdx.x;
    id = (id & 7) * (nwg >> 3) + (id >> 3);
    const int bz  = id / plane;
    const int rem = id - bz * plane;
    const int by  = rem / nbx;
    const int bx  = rem - by * nbx;
    const long bm = (long)by * 256;
    const long bn = (long)bx * 256;
    const long zA = (long)bz * sA, zB = (long)bz * sB;

    const int tid  = threadIdx.x;
    const int lane = tid & 63;
    const int wid  = tid >> 6;
    const int wr   = wid >> 2;
    const int wc   = wid & 3;
    const int fr   = lane & 15;
    const int kg   = lane >> 4;

    const int srow = tid >> 3;
    const int scol = ((tid & 7) ^ ((tid >> 4) & 7)) << 3;
    const int ldsw = wid << 10;

    const int swzb    = (fr & 14) << 3;
    const int koff[2] = { (kg * 16) ^ swzb, (64 + kg * 16) ^ swzb };
    const int aBase   = wr * 16384 + fr * 128;
    const int bBase   = 32768 + (wc >> 1) * 16384 + (wc & 1) * 8192 + fr * 128;

    f32x4 acc[8][4] = {};
    f16x8 bfr[4][2];

    auto stage = [&](int kt, int part, int buf) {
        const int seg    = kt >> 4;
        const int klocal = (kt & 15) << 6;
        const bool isB = part < 2;
        const f16_t* base;
        if (isB) base = (seg == 0) ? B0 : (seg == 1 ? B1 : B2);
        else     base = (seg == 0) ? A0 : (seg == 1 ? A1 : A2);
        const long rowb = (isB ? (bn + part * 128) : (bm + (part - 2) * 128)) + srow;
        const long zoff = isB ? zB : zA;
        const int  ld   = isB ? ldb : lda;
        const int  poff = isB ? (32768 + part * 16384) : ((part - 2) * 16384);
        #pragma unroll
        for (int c = 0; c < 2; ++c) {
            const f16_t* g = base + zoff + (rowb + c * 64) * (long)ld + klocal + scol;
            gld_lds16(g, smem + buf * 65536 + poff + c * 8192 + ldsw);
        }
    };

    #pragma unroll
    for (int ht = 0; ht < 7; ++ht) stage(ht >> 2, ht & 3, (ht >> 2) & 1);
    asm volatile("s_waitcnt vmcnt(6)" ::: "memory");
    __builtin_amdgcn_s_barrier();

    const int NI = NK >> 1;
    #pragma unroll 1
    for (int i = 0; i < NI; ++i) {
        const bool last = (i == NI - 1);
        #pragma unroll
        for (int p = 0; p < 8; ++p) {
            const int q  = p & 3;
            const int cb = (p >> 2) * 65536;
            if (q == 0) {
                #pragma unroll
                for (int fn = 0; fn < 4; ++fn)
                    #pragma unroll
                    for (int kh = 0; kh < 2; ++kh)
                        bfr[fn][kh] = ld128(smem + cb + bBase
                                            + fn * 2048 + koff[kh]);
            }
            f16x8 afr[2][2];
            #pragma unroll
            for (int m2 = 0; m2 < 2; ++m2)
                #pragma unroll
                for (int kh = 0; kh < 2; ++kh)
                    afr[m2][kh] = ld128(smem + cb + aBase
                                        + (q * 2 + m2) * 2048 + koff[kh]);
            const int sc = (7 + p) >> 2;
            if (p == 0 || !last) stage(2 * i + sc, (7 + p) & 3, sc & 1);
            __builtin_amdgcn_s_barrier();
            asm volatile("s_waitcnt lgkmcnt(0)" ::: "memory");
            __builtin_amdgcn_sched_barrier(0);   // rule #18: pin MFMA below wait
            __builtin_amdgcn_s_setprio(1);
            #pragma unroll
            for (int m2 = 0; m2 < 2; ++m2)
                #pragma unroll
                for (int fn = 0; fn < 4; ++fn)
                    #pragma unroll
                    for (int kh = 0; kh < 2; ++kh)
                        acc[q * 2 + m2][fn] = __builtin_amdgcn_mfma_f32_16x16x32_f16(
                            afr[m2][kh], bfr[fn][kh], acc[q * 2 + m2][fn], 0, 0, 0);
            __builtin_amdgcn_s_setprio(0);
            if (q == 3) {
                if (last) asm volatile("s_waitcnt vmcnt(0)" ::: "memory");
                else      asm volatile("s_waitcnt vmcnt(6)" ::: "memory");
            }
            __builtin_amdgcn_s_barrier();
        }
    }

    const int rq = kg * 4;
    #pragma unroll
    for (int m = 0; m < 8; ++m) {
        #pragma unroll
        for (int fn = 0; fn < 4; ++fn) {
            const long col = bn + wc * 64 + fn * 16 + fr;
            #pragma unroll
            for (int r = 0; r < 4; ++r) {
                const long row = bm + wr * 128 + m * 16 + rq + r;
                const float v = acc[m][fn][r];
                if constexpr (EPI == 0) {
                    ((float*)C0v)[(long)bz * sC + row * ldc + col] = v;
                } else {
                    const long off = (col >= 1024)
                        ? 8388608L + row * 1024 + (col - 1024)
                        : row * 1024 + col;
                    ((f16_t*)C0v)[off] = (f16_t)v;
                }
            }
        }
    }
}

// ================= 128x256 BK64 GEMM (uT, PV) — same engine =================
// EPI 0: fp32 C ; EPI 1: fp16 C.  C[bz*sC + row*ldc + col].
template<int EPI>
__global__ __launch_bounds__(512, 1)
void gemm128x256(const f16_t* __restrict__ A, const f16_t* __restrict__ B,
                 int NK, int lda, int ldb, long sA, long sB, long sC,
                 void* __restrict__ C0v, int ldc, int nbx, int plane)
{
    // LDS: 2 buffers x [A 16K | B0 16K | B1 16K] = 96 KiB
    __shared__ __align__(1024) char smem[98304];

    const int nwg = (int)gridDim.x;
    int id = (int)blockIdx.x;
    id = (id & 7) * (nwg >> 3) + (id >> 3);
    const int bz  = id / plane;
    const int rem = id - bz * plane;
    const int by  = rem / nbx;
    const int bx  = rem - by * nbx;
    const long bm = (long)by * 128;
    const long bn = (long)bx * 256;
    const f16_t* Ab = A + (long)bz * sA;
    const f16_t* Bb = B + (long)bz * sB;

    const int tid  = threadIdx.x;
    const int lane = tid & 63;
    const int wid  = tid >> 6;
    const int wr   = wid >> 2;      // M half (2 x 64 rows)
    const int wc   = wid & 3;       // N quarter (4 x 64 cols)
    const int fr   = lane & 15;
    const int kg   = lane >> 4;

    const int srow = tid >> 3;
    const int scol = ((tid & 7) ^ ((tid >> 4) & 7)) << 3;
    const int ldsw = wid << 10;

    const int swzb    = (fr & 14) << 3;
    const int koff[2] = { (kg * 16) ^ swzb, (64 + kg * 16) ^ swzb };
    const int aBase   = wr * 8192 + fr * 128;            // A: rows wr*64..
    const int bBase   = 16384 + wc * 8192 + fr * 128;    // B: rows wc*64..

    f32x4 acc[4][4] = {};
    f16x8 bfr[4][2];

    // part: 0 = B rows [bn,bn+128), 1 = B rows [bn+128,bn+256), 2 = A
    auto stage = [&](int kt, int part, int buf) {
        const bool isB = part < 2;
        const f16_t* base = isB ? Bb : Ab;
        const long rowb = (isB ? (bn + part * 128) : bm) + srow;
        const int  ld   = isB ? ldb : lda;
        const int  poff = isB ? (16384 + part * 16384) : 0;
        #pragma unroll
        for (int c = 0; c < 2; ++c) {
            const f16_t* g = base + (rowb + c * 64) * (long)ld + kt * 64 + scol;
            gld_lds16(g, smem + buf * 49152 + poff + c * 8192 + ldsw);
        }
    };

    // prologue: t0 {B0,B1,A}, t1 {B0,B1}  (t1.A staged at t0.q0)
    stage(0, 0, 0); stage(0, 1, 0); stage(0, 2, 0);
    stage(1, 0, 1); stage(1, 1, 1);
    asm volatile("s_waitcnt vmcnt(4)" ::: "memory");   // t0's 6 gld oldest of 10
    __builtin_amdgcn_s_barrier();

    #pragma unroll 1
    for (int T = 0; T < NK; ++T) {
        const int cb = (T & 1) * 49152;
        #pragma unroll
        for (int q = 0; q < 4; ++q) {
            if (q == 0) {
                #pragma unroll
                for (int fn = 0; fn < 4; ++fn)
                    #pragma unroll
                    for (int kh = 0; kh < 2; ++kh)
                        bfr[fn][kh] = ld128(smem + cb + bBase
                                            + fn * 2048 + koff[kh]);
            }
            f16x8 afr[2];
            #pragma unroll
            for (int kh = 0; kh < 2; ++kh)
                afr[kh] = ld128(smem + cb + aBase + q * 2048 + koff[kh]);
            // staging schedule (regions free by construction; see header)
            if (q == 0 && T + 1 < NK) stage(T + 1, 2, (T + 1) & 1);
            if (q == 1 && T + 2 < NK) stage(T + 2, 0, T & 1);
            if (q == 2 && T + 2 < NK) stage(T + 2, 1, T & 1);
            __builtin_amdgcn_s_barrier();
            asm volatile("s_waitcnt lgkmcnt(0)" ::: "memory");
            __builtin_amdgcn_sched_barrier(0);   // rule #18
            __builtin_amdgcn_s_setprio(1);
            #pragma unroll
            for (int fn = 0; fn < 4; ++fn)
                #pragma unroll
                for (int kh = 0; kh < 2; ++kh)
                    acc[q][fn] = __builtin_amdgcn_mfma_f32_16x16x32_f16(
                        afr[kh], bfr[fn][kh], acc[q][fn], 0, 0, 0);
            __builtin_amdgcn_s_setprio(0);
            if (q == 3) {                        // drain T+1 before its reads
                if (T >= NK - 2) asm volatile("s_waitcnt vmcnt(0)" ::: "memory");
                else             asm volatile("s_waitcnt vmcnt(4)" ::: "memory");
            }
            __builtin_amdgcn_s_barrier();
        }
    }

    const int rq = kg * 4;
    #pragma unroll
    for (int q = 0; q < 4; ++q) {
        #pragma unroll
        for (int fn = 0; fn < 4; ++fn) {
            const long col = bn + wc * 64 + fn * 16 + fr;
            #pragma unroll
            for (int r = 0; r < 4; ++r) {
                const long row = bm + wr * 64 + q * 16 + rq + r;
                const long idx = (long)bz * sC + row * ldc + col;
                const float v = acc[q][fn][r];
                if constexpr (EPI == 0) ((float*)C0v)[idx] = v;
                else                    ((f16_t*)C0v)[idx] = (f16_t)v;
            }
        }
    }
}

// ======================= 128^2 plain GEMM (Wvo only) ========================
#define BM 128
#define BN 128
#define BK 32

template<int EPI>   // 0 = fp32 C ; 1 = fp16 C
__global__ __launch_bounds__(256, 2)
void gemm_nt(const f16_t* __restrict__ A, const f16_t* __restrict__ B,
             int K, int lda, int ldb, long sA, long sB, long sC,
             void* __restrict__ C0v, int ldc, int nbx, int nby)
{
    __shared__ f16_t As[BM * BK];
    __shared__ f16_t Bs[BN * BK];

    const int nwg = (int)gridDim.x;
    int id = (int)blockIdx.x;
    id = (id & 7) * (nwg >> 3) + (id >> 3);
    const int plane = nbx * nby;
    const int bz  = id / plane;
    const int rem = id - bz * plane;
    const int by  = rem / nbx;
    const int bx  = rem - by * nbx;

    const long bm = (long)by * BM;
    const long bn = (long)bx * BN;

    const f16_t* A0 = A + (long)bz * sA;
    const f16_t* B0 = B + (long)bz * sB;

    const int tid  = threadIdx.x;
    const int lane = tid & 63;
    const int wid  = tid >> 6;
    const int wr   = wid >> 1;
    const int wc   = wid & 1;

    const int srow = tid >> 2;
    const int sgc  = (((tid & 3) ^ ((tid >> 3) & 3)) << 3);
    const int ldsb = wid * 512;

    const int fr  = lane & 15;
    const int kgs = (((lane >> 4) ^ ((lane >> 1) & 3)) << 3);

    f32x4 acc[4][4] = {};

    const long arow = (bm + srow) * (long)lda;
    const long brow = (bn + srow) * (long)ldb;

    for (int k0 = 0; k0 < K; k0 += BK) {
        const f16_t* a = A0 + arow + k0 + sgc;
        const f16_t* b = B0 + brow + k0 + sgc;
        gld_lds16(a,             &As[ldsb]);
        gld_lds16(a + 64L * lda, &As[2048 + ldsb]);
        gld_lds16(b,             &Bs[ldsb]);
        gld_lds16(b + 64L * ldb, &Bs[2048 + ldsb]);
        __syncthreads();

        f16x8 af[4], bg[4];
        #pragma unroll
        for (int m = 0; m < 4; ++m)
            af[m] = *(const f16x8*)&As[(wr * 64 + m * 16 + fr) * BK + kgs];
        #pragma unroll
        for (int n = 0; n < 4; ++n)
            bg[n] = *(const f16x8*)&Bs[(wc * 64 + n * 16 + fr) * BK + kgs];
        #pragma unroll
        for (int m = 0; m < 4; ++m)
            #pragma unroll
            for (int n = 0; n < 4; ++n)
                acc[m][n] = __builtin_amdgcn_mfma_f32_16x16x32_f16(
                    af[m], bg[n], acc[m][n], 0, 0, 0);
        __syncthreads();
    }

    const int rq = (lane >> 4) * 4;
    #pragma unroll
    for (int m = 0; m < 4; ++m) {
        #pragma unroll
        for (int n = 0; n < 4; ++n) {
            const long col = bn + wc * 64 + n * 16 + fr;
            #pragma unroll
            for (int r = 0; r < 4; ++r) {
                const long row = bm + wr * 64 + m * 16 + rq + r;
                const long idx = (long)bz * sC + row * ldc + col;
                const float v = acc[m][n][r];
                if constexpr (EPI == 0) ((float*)C0v)[idx] = v;
                else                    ((f16_t*)C0v)[idx] = (f16_t)v;
            }
        }
    }
}

// ==================== fused prep: cvt + split + transpose ===================
__global__ __launch_bounds__(256)
void prep(const float* __restrict__ x,  const float* __restrict__ Wq,
          const float* __restrict__ Wk, const float* __restrict__ Wo,
          const float* __restrict__ Wv,
          f16_t* __restrict__ xh, f16_t* __restrict__ xl,
          f16_t* __restrict__ wqk, f16_t* __restrict__ wo16,
          f16_t* __restrict__ wvT)
{
    const int bid = blockIdx.x;
    const int tid = threadIdx.x;
    if (bid < 4096) {
        const int i = (bid * 256 + tid) * 8;
        const f32x4 v0 = *(const f32x4*)&x[i];
        const f32x4 v1 = *(const f32x4*)&x[i + 4];
        f16x8 h, l;
        #pragma unroll
        for (int j = 0; j < 4; ++j) {
            h[j]     = (f16_t)v0[j];
            l[j]     = (f16_t)(v0[j] - (float)h[j]);
            h[j + 4] = (f16_t)v1[j];
            l[j + 4] = (f16_t)(v1[j] - (float)h[j + 4]);
        }
        *(f16x8*)&xh[i] = h;
        *(f16x8*)&xl[i] = l;
    } else if (bid < 5632) {
        const float* src; f16_t* dst;
        if      (bid < 4608) { src = Wq; dst = wqk;               }
        else if (bid < 5120) { src = Wk; dst = wqk + 1024 * 1024; }
        else                 { src = Wo; dst = wo16;              }
        const int lb = (bid < 4608) ? bid - 4096 : (bid < 5120 ? bid - 4608 : bid - 5120);
        const int i = (lb * 256 + tid) * 8;
        const f32x4 v0 = *(const f32x4*)&src[i];
        const f32x4 v1 = *(const f32x4*)&src[i + 4];
        f16x8 h;
        #pragma unroll
        for (int j = 0; j < 4; ++j) {
            h[j]     = (f16_t)v0[j];
            h[j + 4] = (f16_t)v1[j];
        }
        *(f16x8*)&dst[i] = h;
    } else {
        __shared__ float tile[64][65];
        const int b  = bid - 5632;
        const int br = b >> 4, bc = b & 15;
        const int c  = tid & 63;
        #pragma unroll
        for (int j = 0; j < 16; ++j) {
            const int r = j * 4 + (tid >> 6);
            tile[r][c] = Wv[(br * 64 + r) * 1024 + bc * 64 + c];
        }
        __syncthreads();
        #pragma unroll
        for (int j = 0; j < 16; ++j) {
            const int r = j * 4 + (tid >> 6);
            wvT[(bc * 64 + r) * 1024 + br * 64 + c] = (f16_t)tile[c][r];
        }
    }
}

// row softmax over 2048 cols; one 256-thread block per row; fp32 in, fp16 out
__global__ __launch_bounds__(256)
void softmax_rows(const float* __restrict__ Sc, f16_t* __restrict__ P)
{
    constexpr int NC = 2048;
    const int row = blockIdx.x;
    const int tid = threadIdx.x;
    const float* s = Sc + (size_t)row * NC;

    float v[8];
    *(f32x4*)&v[0] = *(const f32x4*)&s[tid * 8];
    *(f32x4*)&v[4] = *(const f32x4*)&s[tid * 8 + 4];

    float m = v[0];
    #pragma unroll
    for (int j = 1; j < 8; ++j) m = fmaxf(m, v[j]);
    #pragma unroll
    for (int off = 1; off < 64; off <<= 1) m = fmaxf(m, __shfl_xor(m, off));

    __shared__ float redm[4], reds[4];
    if ((tid & 63) == 0) redm[tid >> 6] = m;
    __syncthreads();
    m = fmaxf(fmaxf(redm[0], redm[1]), fmaxf(redm[2], redm[3]));

    float sum = 0.f;
    #pragma unroll
    for (int j = 0; j < 8; ++j) { v[j] = __expf(v[j] - m); sum += v[j]; }
    #pragma unroll
    for (int off = 1; off < 64; off <<= 1) sum += __shfl_xor(sum, off);
    if ((tid & 63) == 0) reds[tid >> 6] = sum;
    __syncthreads();
    sum = reds[0] + reds[1] + reds[2] + reds[3];

    const float inv = 1.0f / sum;
    f16x8 o;
    #pragma unroll
    for (int j = 0; j < 8; ++j) o[j] = (f16_t)(v[j] * inv);
    *(f16x8*)(P + (size_t)row * NC + tid * 8) = o;
}

// =========================== driver =========================================
extern "C" void kernel_launch(void* const* d_in, const int* in_sizes, int n_in,
                              void* d_out, int out_size, void* d_ws, size_t ws_size,
                              hipStream_t stream)
{
    const float* x  = (const float*)d_in[0];
    const float* Wq = (const float*)d_in[1];
    const float* Wk = (const float*)d_in[2];
    const float* Wv = (const float*)d_in[3];
    const float* Wo = (const float*)d_in[4];
    float* out = (float*)d_out;

    constexpr long H = 1024, S = 2048, B = 4, NT = B * S;

    char* ws = (char*)d_ws;
    const size_t MB = 1u << 20;
    f16_t* xh    = (f16_t*)(ws + 0);
    float* score = (float*)(ws + 0);
    f16_t* wqk   = (f16_t*)(ws + 64 * MB);
    f16_t* wo16  = (f16_t*)(ws + 68 * MB);
    f16_t* wvT   = (f16_t*)(ws + 70 * MB);
    f16_t* wvo   = (f16_t*)(ws + 72 * MB);
    f16_t* qh    = (f16_t*)(ws + 80 * MB);
    f16_t* kh    = (f16_t*)(ws + 96 * MB);   // = qh + 8388608 elems
    f16_t* P     = (f16_t*)(ws + 80 * MB);   // after score (qh/kh dead)
    f16_t* uT    = (f16_t*)(ws + 112 * MB);
    f16_t* xl    = (f16_t*)(ws + 128 * MB);

    // 1. fused conversions/splits/transpose
    prep<<<dim3(5888), dim3(256), 0, stream>>>(x, Wq, Wk, Wo, Wv,
                                               xh, xl, wqk, wo16, wvT);

    // 2. q,k projection: 2 segments, virtual K=2048, fp16 col-split epilogue
    gemm256<3><<<dim3(256), dim3(512), 0, stream>>>(
        xh, xl, xh, wqk, wqk, wqk, 32, (int)H, (int)H, 0L, 0L, 0L,
        qh, (int)H, 8, 256);

    // 3. Wvo[f][d] = sum_e Wo[f][e] Wv[e][d]   (tiny: 64 blocks)
    gemm_nt<1><<<dim3(64), dim3(256), 0, stream>>>(
        wo16, wvT, (int)H, (int)H, (int)H, 0L, 0L, 0L, wvo, (int)H, 8, 8);

    // 4. uT[f][t] = sum_d Wvo[f][d] x[t][d]   (128x256 engine, 256 blocks)
    gemm128x256<1><<<dim3(256), dim3(512), 0, stream>>>(
        wvo, xh, 16, (int)H, (int)H, 0L, 0L, 0L, uT, (int)NT, 32, 256);

    // 5. score = q k^T, 1 segment, all 4 batches (fp32, unscaled)
    gemm256<0><<<dim3(256), dim3(512), 0, stream>>>(
        qh, qh, qh, kh, kh, kh, 16, (int)H, (int)H,
        S * H, S * H, S * S, score, (int)S, 8, 64);

    // 6. softmax rows
    softmax_rows<<<dim3(B * S), dim3(256), 0, stream>>>(score, P);

    // 7. out = P * uT-slice^T  (128x256 engine, 256 blocks, fp32 to d_out)
    gemm128x256<0><<<dim3(256), dim3(512), 0, stream>>>(
        P, uT, 32, (int)S, (int)NT, S * S, S, S * H, out, (int)H, 4, 64);
}